// Round 4
// baseline (5323.952 us; speedup 1.0000x reference)
//
#include <hip/hip_runtime.h>
#include <cstddef>

// Problem constants
#define TT    32       // T_ENC
#define DD    512      // D_IN
#define HH    256      // hidden
#define NCLS  38       // classes
#define NSTEP 26       // MAXLEN+1
#define NKC   26       // K chunks of 32 for gates GEMM (16 ctx + 2 onehot + 8 h)

typedef float f32x4 __attribute__((ext_vector_type(4)));
typedef short bf16x8 __attribute__((ext_vector_type(8)));
typedef unsigned int u32x4 __attribute__((ext_vector_type(4)));

__device__ __forceinline__ float fast_tanh(float z) {
  float e = __expf(2.f * z);
  return 1.f - 2.f / (e + 1.f);
}
__device__ __forceinline__ float fast_sigmoid(float z) {
  return 1.f / (1.f + __expf(-z));
}
__device__ __forceinline__ float bf2f(unsigned short s) {
  union { unsigned int u; float f; } v; v.u = ((unsigned int)s) << 16; return v.f;
}
__device__ __forceinline__ unsigned short f2bf(float f) {  // RNE
  union { float ff; unsigned int u; } v; v.ff = f;
  unsigned int r = v.u + 0x7FFFu + ((v.u >> 16) & 1u);
  return (unsigned short)(r >> 16);
}
__device__ __forceinline__ unsigned int pk(unsigned short a, unsigned short b) {
  return (unsigned int)a | ((unsigned int)b << 16);
}

// ---------------------------------------------------------------------------
// batch_H fp32 -> bf16 row-major (33,554,432 elems; 8 per thread; grid 16384)
__global__ __launch_bounds__(256) void cvt_bh_kernel(const float* __restrict__ src,
                                                     unsigned short* __restrict__ dst) {
  int t = blockIdx.x * 256 + threadIdx.x;
  const float4* s4 = (const float4*)src + (size_t)t * 2;
  float4 a = s4[0], b = s4[1];
  uint4 o;
  o.x = pk(f2bf(a.x), f2bf(a.y));
  o.y = pk(f2bf(a.z), f2bf(a.w));
  o.z = pk(f2bf(b.x), f2bf(b.y));
  o.w = pk(f2bf(b.z), f2bf(b.w));
  ((uint4*)dst)[t] = o;
}

// gates weights bf16, MFMA-B swizzled [nt(64)][kc(26)][lane][8].
// col = nt*16 + li ; gate = nt&3 ; jg = (nt>>2)*16 + li
__global__ __launch_bounds__(256) void prep_wg_kernel(const float* __restrict__ W_ih,
                                                      const float* __restrict__ W_hh,
                                                      unsigned short* __restrict__ Wg) {
  int flat = blockIdx.x * 256 + threadIdx.x;   // 64*NKC*64 = 106496
  if (flat >= 64 * NKC * 64) return;
  int l = flat & 63, ntkc = flat >> 6;
  int nt = ntkc / NKC, kc = ntkc - nt * NKC;
  int gate = nt & 3;
  int jg = (nt >> 2) * 16 + (l & 15);
  int orig = gate * 256 + jg;
  int kbase = kc * 32 + (l >> 4) * 8;
  unsigned short e[8];
#pragma unroll
  for (int j = 0; j < 8; ++j) {
    int k = kbase + j;
    float v;
    if (k < DD + NCLS)      v = W_ih[orig * (DD + NCLS) + k];
    else if (k < 576)       v = 0.f;                       // pad 550..575
    else                    v = W_hh[orig * HH + (k - 576)];
    e[j] = f2bf(v);
  }
  uint4 o = {pk(e[0], e[1]), pk(e[2], e[3]), pk(e[4], e[5]), pk(e[6], e[7])};
  ((uint4*)Wg)[flat] = o;
}

// W_i2h [256][512] -> bf16 MFMA-B swizzled [nt(16)][kc(16)][lane][8]
__global__ __launch_bounds__(256) void prep_wi_kernel(const float* __restrict__ W_i2h,
                                                      unsigned short* __restrict__ Wi) {
  int flat = blockIdx.x * 256 + threadIdx.x;   // 16*16*64 = 16384
  int l = flat & 63, ntkc = flat >> 6;
  int nt = ntkc >> 4, kc = ntkc & 15;
  int n = nt * 16 + (l & 15);
  int kbase = kc * 32 + (l >> 4) * 8;
  unsigned short e[8];
#pragma unroll
  for (int j = 0; j < 8; ++j) e[j] = f2bf(W_i2h[(size_t)n * DD + kbase + j]);
  uint4 o = {pk(e[0], e[1]), pk(e[2], e[3]), pk(e[4], e[5]), pk(e[6], e[7])};
  ((uint4*)Wi)[flat] = o;
}

// W_gen [38][256] -> bf16 MFMA-B swizzled [nt(3)][kc(8)][lane][8], cols padded to 48
__global__ __launch_bounds__(256) void prep_wgen_kernel(const float* __restrict__ W_gen,
                                                        unsigned short* __restrict__ Wgp) {
  int flat = blockIdx.x * 256 + threadIdx.x;   // 3*8*64 = 1536
  if (flat >= 1536) return;
  int l = flat & 63, ntkc = flat >> 6;
  int nt = ntkc >> 3, kc = ntkc & 7;
  int n = nt * 16 + (l & 15);
  int kbase = kc * 32 + (l >> 4) * 8;
  unsigned short e[8];
#pragma unroll
  for (int j = 0; j < 8; ++j)
    e[j] = (n < NCLS) ? f2bf(W_gen[(size_t)n * HH + kbase + j]) : (unsigned short)0;
  uint4 o = {pk(e[0], e[1]), pk(e[2], e[3]), pk(e[4], e[5]), pk(e[6], e[7])};
  ((uint4*)Wgp)[flat] = o;
}

// W_h2h [256][256] -> bf16 MFMA-B swizzled [nt(16)][kc(8)][lane][8]; plus bc = b_ih+b_hh
__global__ __launch_bounds__(256) void prep_whb_bc_kernel(const float* __restrict__ W_h2h,
                                                          const float* __restrict__ b_ih,
                                                          const float* __restrict__ b_hh,
                                                          unsigned short* __restrict__ Whb,
                                                          float* __restrict__ bc) {
  int flat = blockIdx.x * 256 + threadIdx.x;   // 16*8*64 = 8192
  if (flat >= 8192) return;
  int l = flat & 63, ntkc = flat >> 6;
  int nt = ntkc >> 3, kc = ntkc & 7;
  int n = nt * 16 + (l & 15);
  int kbase = kc * 32 + (l >> 4) * 8;
  unsigned short e[8];
#pragma unroll
  for (int j = 0; j < 8; ++j) e[j] = f2bf(W_h2h[(size_t)n * HH + kbase + j]);
  uint4 o = {pk(e[0], e[1]), pk(e[2], e[3]), pk(e[4], e[5]), pk(e[6], e[7])};
  ((uint4*)Whb)[flat] = o;
  if (flat < 1024) bc[flat] = b_ih[flat] + b_hh[flat];
}

// ---------------------------------------------------------------------------
// H_proj = batch_H(bf16) @ W_i2h^T -> bf16 [65536][256]; 512 blocks * 128 rows
__global__ __launch_bounds__(256) void hproj_mfma_kernel(const unsigned short* __restrict__ Abf,
                                                         const unsigned short* __restrict__ Wi,
                                                         unsigned short* __restrict__ Hbf) {
  const int tid = threadIdx.x;
  const int w = tid >> 6, l = tid & 63;
  const int li = l & 15, qd = l >> 4;
  const int m0 = blockIdx.x * 128 + w * 32;
  f32x4 acc[2][16];
#pragma unroll
  for (int a = 0; a < 2; ++a)
#pragma unroll
    for (int b = 0; b < 16; ++b) acc[a][b] = (f32x4){0.f, 0.f, 0.f, 0.f};
  const bf16x8* Wi8 = (const bf16x8*)Wi;
  for (int kc = 0; kc < 16; ++kc) {
    bf16x8 a0 = *(const bf16x8*)(Abf + (size_t)(m0 + li) * DD + kc * 32 + qd * 8);
    bf16x8 a1 = *(const bf16x8*)(Abf + (size_t)(m0 + 16 + li) * DD + kc * 32 + qd * 8);
#pragma unroll
    for (int nt = 0; nt < 16; ++nt) {
      bf16x8 b = Wi8[(nt * 16 + kc) * 64 + l];
      acc[0][nt] = __builtin_amdgcn_mfma_f32_16x16x32_bf16(a0, b, acc[0][nt], 0, 0, 0);
      acc[1][nt] = __builtin_amdgcn_mfma_f32_16x16x32_bf16(a1, b, acc[1][nt], 0, 0, 0);
    }
  }
#pragma unroll
  for (int mi = 0; mi < 2; ++mi)
#pragma unroll
    for (int nt = 0; nt < 16; ++nt)
#pragma unroll
      for (int r = 0; r < 4; ++r) {
        int row = m0 + mi * 16 + qd * 4 + r;
        Hbf[(size_t)row * HH + nt * 16 + li] = f2bf(acc[mi][nt][r]);
      }
}

// ---------------------------------------------------------------------------
// Persistent fused decode: 256 blocks x 512 threads; block owns rows 8b..8b+7.
// All 26 steps run inside; zero cross-block communication.
//
// LDS layout (dynamic, 162816 B):
#define LDS_HP    0        // 131072: H_proj bf16 [it=256][j=256], byte ^= (it&7)<<4
#define LDS_XA    131072   //  18432: gates-A chunks [kc=18][lane=64][8bf16], XOR-swz
#define LDS_HL    149504   //   4096: h bf16 [row=8][256], byte ^= (row&7)<<4
#define LDS_HPF   153600   //   8192: hp f32 [8][256]
#define LDS_SE    161792   //   1024: e/alpha f32 [8][32]
#define LDS_TOTAL 162816

__global__ __launch_bounds__(512)
__attribute__((amdgpu_waves_per_eu(2, 2)))
void decode_kernel(
    const unsigned short* __restrict__ bHbf, const unsigned short* __restrict__ Hbf,
    const unsigned short* __restrict__ Wg, const unsigned short* __restrict__ Whb,
    const unsigned short* __restrict__ Wgp, const float* __restrict__ bc,
    const float* __restrict__ b_h2h, const float* __restrict__ W_score,
    const float* __restrict__ b_gen, const int* __restrict__ text,
    float* __restrict__ out) {
  extern __shared__ char lds[];
  char* HP = lds + LDS_HP;
  char* XA = lds + LDS_XA;
  char* HL = lds + LDS_HL;
  float* HPF = (float*)(lds + LDS_HPF);
  float* SE = (float*)(lds + LDS_SE);

  const int tid = threadIdx.x;
  const int w = tid >> 6, ln = tid & 63;
  const int li = ln & 15, qd = ln >> 4;
  const int b0 = blockIdx.x * 8;
  const int hrow = ln & 7;   // MFMA A-frag h-row (rows 8..15 duplicate 0..7, discarded)

  // ---- init: zero XA + HL (contiguous, 22528 B)
  for (int off = tid; off < (18432 + 4096) / 4; off += 512) ((float*)XA)[off] = 0.f;

  // ---- load batch_H slice into registers: wave w = row w, lane ln = d-slice 8*ln..+8
  u32x4 bh[TT];
  {
    const u32x4* src = (const u32x4*)(bHbf + (size_t)(b0 + w) * TT * DD) + ln;
#pragma unroll
    for (int t = 0; t < TT; ++t) bh[t] = src[t * 64];
  }
  // Pin bh in registers: values become asm outputs -> backend cannot
  // rematerialize the global loads inside the step loop.
#pragma unroll
  for (int t = 0; t < TT; ++t) asm volatile("" : "+v"(bh[t]));

  // ---- load H_proj slice into LDS (row-XOR swizzled: byte ^= (it&7)<<4)
  {
    const uint4* src = (const uint4*)(Hbf + (size_t)b0 * TT * HH);
    for (int it8 = 0; it8 < 16; ++it8) {
      int flat = it8 * 512 + tid;
      int it = flat >> 5, j8 = flat & 31;
      uint4 v = src[(size_t)it * 32 + j8];
      *(uint4*)(HP + it * 512 + ((j8 * 16) ^ ((it & 7) << 4))) = v;
    }
  }
  f32x4 cst[2] = {{0.f, 0.f, 0.f, 0.f}, {0.f, 0.f, 0.f, 0.f}};  // c state
  __syncthreads();

  for (int s = 0; s < NSTEP; ++s) {
    // ---- A: hp = h @ W_h2h^T + b_h2h  (16-row M-tile, 8 valid; wave w -> nt 2w..2w+1)
    {
      f32x4 hacc[2] = {{0.f, 0.f, 0.f, 0.f}, {0.f, 0.f, 0.f, 0.f}};
      const bf16x8* WB = (const bf16x8*)Whb;
#pragma unroll
      for (int kc = 0; kc < 8; ++kc) {
        bf16x8 a = *(const bf16x8*)(HL + hrow * 512 + ((kc * 64 + qd * 16) ^ (hrow << 4)));
#pragma unroll
        for (int n = 0; n < 2; ++n) {
          bf16x8 b = WB[((w * 2 + n) * 8 + kc) * 64 + ln];
          hacc[n] = __builtin_amdgcn_mfma_f32_16x16x32_bf16(a, b, hacc[n], 0, 0, 0);
        }
      }
      if (qd < 2) {
#pragma unroll
        for (int n = 0; n < 2; ++n) {
          int col = (w * 2 + n) * 16 + li;
          float bb = b_h2h[col];
#pragma unroll
          for (int r = 0; r < 4; ++r) HPF[(qd * 4 + r) * 256 + col] = hacc[n][r] + bb;
        }
      }
    }
    __syncthreads();

    // ---- B: e[i][t] = sum_j tanh(HP + hp) * ws  (8-lane groups, 4 passes)
    {
      const int sub = ln >> 3, li8 = ln & 7;
#pragma unroll
      for (int p = 0; p < 4; ++p) {
        int pi = p * 64 + w * 8 + sub;       // it = i*32 + t
        int i = pi >> 5, t = pi & 31;
        const char* hpb = HP + pi * 512;
        const int swz = (pi & 7) << 4;
        float v = 0.f;
#pragma unroll
        for (int c = 0; c < 4; ++c) {
          int j = c * 64 + li8 * 8;
          uint4 hv = *(const uint4*)(hpb + ((j * 2) ^ swz));
          float4 hp0 = *(const float4*)(HPF + i * 256 + j);
          float4 hp1 = *(const float4*)(HPF + i * 256 + j + 4);
          float4 ws0 = *(const float4*)(W_score + j);
          float4 ws1 = *(const float4*)(W_score + j + 4);
          v += fast_tanh(bf2f((unsigned short)(hv.x & 0xFFFF)) + hp0.x) * ws0.x;
          v += fast_tanh(bf2f((unsigned short)(hv.x >> 16))    + hp0.y) * ws0.y;
          v += fast_tanh(bf2f((unsigned short)(hv.y & 0xFFFF)) + hp0.z) * ws0.z;
          v += fast_tanh(bf2f((unsigned short)(hv.y >> 16))    + hp0.w) * ws0.w;
          v += fast_tanh(bf2f((unsigned short)(hv.z & 0xFFFF)) + hp1.x) * ws1.x;
          v += fast_tanh(bf2f((unsigned short)(hv.z >> 16))    + hp1.y) * ws1.y;
          v += fast_tanh(bf2f((unsigned short)(hv.w & 0xFFFF)) + hp1.z) * ws1.z;
          v += fast_tanh(bf2f((unsigned short)(hv.w >> 16))    + hp1.w) * ws1.w;
        }
        v += __shfl_xor(v, 1, 64);
        v += __shfl_xor(v, 2, 64);
        v += __shfl_xor(v, 4, 64);
        if (li8 == 0) SE[pi] = v;   // SE[i*32+t]
      }
    }
    __syncthreads();

    // ---- C: softmax over t (32-lane groups)
    if (tid < 256) {
      float e = SE[tid];
      float mx = e;
#pragma unroll
      for (int m = 16; m >= 1; m >>= 1) mx = fmaxf(mx, __shfl_xor(mx, m, 32));
      float pexp = __expf(e - mx);
      float ssum = pexp;
#pragma unroll
      for (int m = 16; m >= 1; m >>= 1) ssum += __shfl_xor(ssum, m, 32);
      SE[tid] = pexp / ssum;
    }
    __syncthreads();

    // ---- D: context from registers -> XA ctx chunks (swizzled); onehot -> kc 16,17
    {
      float acc[8] = {0.f, 0.f, 0.f, 0.f, 0.f, 0.f, 0.f, 0.f};
      const float* al = SE + w * 32;
#pragma unroll
      for (int t = 0; t < TT; ++t) {
        float a = al[t];
        u32x4 hv = bh[t];
        acc[0] += a * bf2f((unsigned short)(hv.x & 0xFFFF));
        acc[1] += a * bf2f((unsigned short)(hv.x >> 16));
        acc[2] += a * bf2f((unsigned short)(hv.y & 0xFFFF));
        acc[3] += a * bf2f((unsigned short)(hv.y >> 16));
        acc[4] += a * bf2f((unsigned short)(hv.z & 0xFFFF));
        acc[5] += a * bf2f((unsigned short)(hv.z >> 16));
        acc[6] += a * bf2f((unsigned short)(hv.w & 0xFFFF));
        acc[7] += a * bf2f((unsigned short)(hv.w >> 16));
      }
      uint4 o = {pk(f2bf(acc[0]), f2bf(acc[1])), pk(f2bf(acc[2]), f2bf(acc[3])),
                 pk(f2bf(acc[4]), f2bf(acc[5])), pk(f2bf(acc[6]), f2bf(acc[7]))};
      int kc = ln >> 2, q = ln & 3;
      int lane_t = q * 16 + w;
      *(uint4*)(XA + kc * 1024 + ((lane_t * 16) ^ ((kc & 7) << 4))) = o;
    }
    if (tid < 64) {
      int row = tid >> 3, sl = tid & 7;
      int kc = 16 + (sl >> 2), q = sl & 3;
      int cc0 = (sl >> 2) * 32 + q * 8;     // onehot class base for this slot
      int ch = text[(b0 + row) * NSTEP + s];
      unsigned short e8[8];
#pragma unroll
      for (int j = 0; j < 8; ++j)
        e8[j] = (cc0 + j == ch) ? (unsigned short)0x3F80 : (unsigned short)0;
      uint4 o = {pk(e8[0], e8[1]), pk(e8[2], e8[3]), pk(e8[4], e8[5]), pk(e8[6], e8[7])};
      int lane_t = q * 16 + row;
      *(uint4*)(XA + kc * 1024 + ((lane_t * 16) ^ ((kc & 7) << 4))) = o;
    }
    __syncthreads();

    // ---- E: gates MFMA (M-tile 16, 8 valid rows; wave w -> nt 8w..8w+7) + cell
    f32x4 acc[8];
#pragma unroll
    for (int n = 0; n < 8; ++n) acc[n] = (f32x4){0.f, 0.f, 0.f, 0.f};
    {
      const bf16x8* W8 = (const bf16x8*)Wg;
      for (int kc = 0; kc < NKC; ++kc) {
        bf16x8 a;
        if (kc < 18) {
          a = *(const bf16x8*)(XA + kc * 1024 + ((ln * 16) ^ ((kc & 7) << 4)));
        } else {
          int kk = (kc - 18) * 64 + qd * 16;
          a = *(const bf16x8*)(HL + hrow * 512 + (kk ^ (hrow << 4)));
        }
#pragma unroll
        for (int n = 0; n < 8; ++n) {
          bf16x8 b = W8[((size_t)(w * 8 + n) * NKC + kc) * 64 + ln];
          acc[n] = __builtin_amdgcn_mfma_f32_16x16x32_bf16(a, b, acc[n], 0, 0, 0);
        }
      }
    }
    unsigned short hreg[2][4];
    if (qd < 2) {
#pragma unroll
      for (int k = 0; k < 2; ++k) {
        int jg = (2 * w + k) * 16 + li;
        float bci = bc[jg], bcf = bc[256 + jg], bcg = bc[512 + jg], bco = bc[768 + jg];
#pragma unroll
        for (int r = 0; r < 4; ++r) {
          float iv = fast_sigmoid(acc[k * 4 + 0][r] + bci);
          float fv = fast_sigmoid(acc[k * 4 + 1][r] + bcf);
          float gv = fast_tanh   (acc[k * 4 + 2][r] + bcg);
          float ov = fast_sigmoid(acc[k * 4 + 3][r] + bco);
          float cn = fv * cst[k][r] + iv * gv;
          cst[k][r] = cn;
          hreg[k][r] = f2bf(ov * fast_tanh(cn));
        }
      }
    }
    __syncthreads();   // all MFMA reads of h(s-1) complete before overwrite

    // ---- F: write h(s) to HL (swizzled)
    if (qd < 2) {
#pragma unroll
      for (int k = 0; k < 2; ++k) {
        int jg = (2 * w + k) * 16 + li;
#pragma unroll
        for (int r = 0; r < 4; ++r) {
          int row = qd * 4 + r;
          *(unsigned short*)(HL + row * 512 + ((jg * 2) ^ (row << 4))) = hreg[k][r];
        }
      }
    }
    __syncthreads();

    // ---- G: probs(s) = h(s) @ W_gen^T + b_gen (waves 0..2; no barrier needed after)
    if (w < 3) {
      f32x4 pa = {0.f, 0.f, 0.f, 0.f};
      const bf16x8* W8 = (const bf16x8*)Wgp;
#pragma unroll
      for (int kc = 0; kc < 8; ++kc) {
        bf16x8 a = *(const bf16x8*)(HL + hrow * 512 + ((kc * 64 + qd * 16) ^ (hrow << 4)));
        bf16x8 b = W8[(w * 8 + kc) * 64 + ln];
        pa = __builtin_amdgcn_mfma_f32_16x16x32_bf16(a, b, pa, 0, 0, 0);
      }
      int col = w * 16 + li;
      if (qd < 2 && col < NCLS) {
        float bg = b_gen[col];
#pragma unroll
        for (int r = 0; r < 4; ++r) {
          int row = qd * 4 + r;
          out[((size_t)(b0 + row) * NSTEP + s) * NCLS + col] = pa[r] + bg;
        }
      }
    }
  }
}

// ---------------------------------------------------------------------------
extern "C" void kernel_launch(void* const* d_in, const int* in_sizes, int n_in,
                              void* d_out, int out_size, void* d_ws, size_t ws_size,
                              hipStream_t stream) {
  const float* batch_H = (const float*)d_in[0];
  const int*   text    = (const int*)d_in[1];
  const float* W_i2h   = (const float*)d_in[2];
  const float* W_h2h   = (const float*)d_in[3];
  const float* b_h2h   = (const float*)d_in[4];
  const float* W_score = (const float*)d_in[5];
  const float* W_ih    = (const float*)d_in[6];
  const float* b_ih    = (const float*)d_in[7];
  const float* W_hh    = (const float*)d_in[8];
  const float* b_hh    = (const float*)d_in[9];
  const float* W_gen   = (const float*)d_in[10];
  const float* b_gen   = (const float*)d_in[11];
  float* out = (float*)d_out;

  // workspace layout (bytes)
  char* p = (char*)d_ws;
  unsigned short* bHbf = (unsigned short*)p;  p += (size_t)2048 * 32 * 512 * 2;  // 64 MiB
  unsigned short* Hbf  = (unsigned short*)p;  p += (size_t)65536 * 256 * 2;      // 32 MiB
  unsigned short* Wg   = (unsigned short*)p;  p += (size_t)64 * NKC * 64 * 8 * 2;
  unsigned short* Wi   = (unsigned short*)p;  p += (size_t)256 * 512 * 2;
  unsigned short* Wgp  = (unsigned short*)p;  p += (size_t)3 * 8 * 64 * 8 * 2;
  unsigned short* Whb  = (unsigned short*)p;  p += (size_t)16 * 8 * 64 * 8 * 2;
  float* bc            = (float*)p;           p += (size_t)1024 * 4;

  static int attr_done = 0;
  if (!attr_done) {
    hipFuncSetAttribute((const void*)decode_kernel,
                        hipFuncAttributeMaxDynamicSharedMemorySize, LDS_TOTAL);
    attr_done = 1;
  }

  cvt_bh_kernel<<<16384, 256, 0, stream>>>(batch_H, bHbf);
  prep_wg_kernel<<<416, 256, 0, stream>>>(W_ih, W_hh, Wg);
  prep_wi_kernel<<<64, 256, 0, stream>>>(W_i2h, Wi);
  prep_wgen_kernel<<<6, 256, 0, stream>>>(W_gen, Wgp);
  prep_whb_bc_kernel<<<32, 256, 0, stream>>>(W_h2h, b_ih, b_hh, Whb, bc);
  hproj_mfma_kernel<<<512, 256, 0, stream>>>(bHbf, Wi, Hbf);
  decode_kernel<<<256, 512, LDS_TOTAL, stream>>>(bHbf, Hbf, Wg, Whb, Wgp, bc,
                                                 b_h2h, W_score, b_gen, text, out);
}

// Round 5
// 5320.250 us; speedup vs baseline: 1.0007x; 1.0007x over previous
//
#include <hip/hip_runtime.h>
#include <cstddef>

// Problem constants
#define TT    32       // T_ENC
#define DD    512      // D_IN
#define HH    256      // hidden
#define NCLS  38       // classes
#define NSTEP 26       // MAXLEN+1
#define NKC   26       // K chunks of 32 for gates GEMM (16 ctx + 2 onehot + 8 h)

typedef float f32x4 __attribute__((ext_vector_type(4)));
typedef short bf16x8 __attribute__((ext_vector_type(8)));
typedef unsigned int u32x4 __attribute__((ext_vector_type(4)));

__device__ __forceinline__ float fast_tanh(float z) {
  float e = __expf(2.f * z);
  return 1.f - 2.f / (e + 1.f);
}
__device__ __forceinline__ float fast_sigmoid(float z) {
  return 1.f / (1.f + __expf(-z));
}
__device__ __forceinline__ float bf2f(unsigned short s) {
  union { unsigned int u; float f; } v; v.u = ((unsigned int)s) << 16; return v.f;
}
__device__ __forceinline__ unsigned short f2bf(float f) {  // RNE
  union { float ff; unsigned int u; } v; v.ff = f;
  unsigned int r = v.u + 0x7FFFu + ((v.u >> 16) & 1u);
  return (unsigned short)(r >> 16);
}
__device__ __forceinline__ unsigned int pk(unsigned short a, unsigned short b) {
  return (unsigned int)a | ((unsigned int)b << 16);
}

// ---------------------------------------------------------------------------
// batch_H fp32 -> bf16 row-major (33,554,432 elems; 8 per thread; grid 16384)
__global__ __launch_bounds__(256) void cvt_bh_kernel(const float* __restrict__ src,
                                                     unsigned short* __restrict__ dst) {
  int t = blockIdx.x * 256 + threadIdx.x;
  const float4* s4 = (const float4*)src + (size_t)t * 2;
  float4 a = s4[0], b = s4[1];
  uint4 o;
  o.x = pk(f2bf(a.x), f2bf(a.y));
  o.y = pk(f2bf(a.z), f2bf(a.w));
  o.z = pk(f2bf(b.x), f2bf(b.y));
  o.w = pk(f2bf(b.z), f2bf(b.w));
  ((uint4*)dst)[t] = o;
}

// gates weights bf16, MFMA-B swizzled [nt(64)][kc(26)][lane][8].
// col = nt*16 + li ; gate = nt&3 ; jg = (nt>>2)*16 + li
__global__ __launch_bounds__(256) void prep_wg_kernel(const float* __restrict__ W_ih,
                                                      const float* __restrict__ W_hh,
                                                      unsigned short* __restrict__ Wg) {
  int flat = blockIdx.x * 256 + threadIdx.x;   // 64*NKC*64 = 106496
  if (flat >= 64 * NKC * 64) return;
  int l = flat & 63, ntkc = flat >> 6;
  int nt = ntkc / NKC, kc = ntkc - nt * NKC;
  int gate = nt & 3;
  int jg = (nt >> 2) * 16 + (l & 15);
  int orig = gate * 256 + jg;
  int kbase = kc * 32 + (l >> 4) * 8;
  unsigned short e[8];
#pragma unroll
  for (int j = 0; j < 8; ++j) {
    int k = kbase + j;
    float v;
    if (k < DD + NCLS)      v = W_ih[orig * (DD + NCLS) + k];
    else if (k < 576)       v = 0.f;                       // pad 550..575
    else                    v = W_hh[orig * HH + (k - 576)];
    e[j] = f2bf(v);
  }
  uint4 o = {pk(e[0], e[1]), pk(e[2], e[3]), pk(e[4], e[5]), pk(e[6], e[7])};
  ((uint4*)Wg)[flat] = o;
}

// W_i2h [256][512] -> bf16 MFMA-B swizzled [nt(16)][kc(16)][lane][8]
__global__ __launch_bounds__(256) void prep_wi_kernel(const float* __restrict__ W_i2h,
                                                      unsigned short* __restrict__ Wi) {
  int flat = blockIdx.x * 256 + threadIdx.x;   // 16*16*64 = 16384
  int l = flat & 63, ntkc = flat >> 6;
  int nt = ntkc >> 4, kc = ntkc & 15;
  int n = nt * 16 + (l & 15);
  int kbase = kc * 32 + (l >> 4) * 8;
  unsigned short e[8];
#pragma unroll
  for (int j = 0; j < 8; ++j) e[j] = f2bf(W_i2h[(size_t)n * DD + kbase + j]);
  uint4 o = {pk(e[0], e[1]), pk(e[2], e[3]), pk(e[4], e[5]), pk(e[6], e[7])};
  ((uint4*)Wi)[flat] = o;
}

// W_gen [38][256] -> bf16 MFMA-B swizzled [nt(3)][kc(8)][lane][8], cols padded to 48
__global__ __launch_bounds__(256) void prep_wgen_kernel(const float* __restrict__ W_gen,
                                                        unsigned short* __restrict__ Wgp) {
  int flat = blockIdx.x * 256 + threadIdx.x;   // 3*8*64 = 1536
  if (flat >= 1536) return;
  int l = flat & 63, ntkc = flat >> 6;
  int nt = ntkc >> 3, kc = ntkc & 7;
  int n = nt * 16 + (l & 15);
  int kbase = kc * 32 + (l >> 4) * 8;
  unsigned short e[8];
#pragma unroll
  for (int j = 0; j < 8; ++j)
    e[j] = (n < NCLS) ? f2bf(W_gen[(size_t)n * HH + kbase + j]) : (unsigned short)0;
  uint4 o = {pk(e[0], e[1]), pk(e[2], e[3]), pk(e[4], e[5]), pk(e[6], e[7])};
  ((uint4*)Wgp)[flat] = o;
}

// W_h2h [256][256] -> bf16 MFMA-B swizzled [nt(16)][kc(8)][lane][8]; plus bc = b_ih+b_hh
__global__ __launch_bounds__(256) void prep_whb_bc_kernel(const float* __restrict__ W_h2h,
                                                          const float* __restrict__ b_ih,
                                                          const float* __restrict__ b_hh,
                                                          unsigned short* __restrict__ Whb,
                                                          float* __restrict__ bc) {
  int flat = blockIdx.x * 256 + threadIdx.x;   // 16*8*64 = 8192
  if (flat >= 8192) return;
  int l = flat & 63, ntkc = flat >> 6;
  int nt = ntkc >> 3, kc = ntkc & 7;
  int n = nt * 16 + (l & 15);
  int kbase = kc * 32 + (l >> 4) * 8;
  unsigned short e[8];
#pragma unroll
  for (int j = 0; j < 8; ++j) e[j] = f2bf(W_h2h[(size_t)n * HH + kbase + j]);
  uint4 o = {pk(e[0], e[1]), pk(e[2], e[3]), pk(e[4], e[5]), pk(e[6], e[7])};
  ((uint4*)Whb)[flat] = o;
  if (flat < 1024) bc[flat] = b_ih[flat] + b_hh[flat];
}

// ---------------------------------------------------------------------------
// H_proj = batch_H(bf16) @ W_i2h^T -> bf16 [65536][256]; 512 blocks * 128 rows
__global__ __launch_bounds__(256) void hproj_mfma_kernel(const unsigned short* __restrict__ Abf,
                                                         const unsigned short* __restrict__ Wi,
                                                         unsigned short* __restrict__ Hbf) {
  const int tid = threadIdx.x;
  const int w = tid >> 6, l = tid & 63;
  const int li = l & 15, qd = l >> 4;
  const int m0 = blockIdx.x * 128 + w * 32;
  f32x4 acc[2][16];
#pragma unroll
  for (int a = 0; a < 2; ++a)
#pragma unroll
    for (int b = 0; b < 16; ++b) acc[a][b] = (f32x4){0.f, 0.f, 0.f, 0.f};
  const bf16x8* Wi8 = (const bf16x8*)Wi;
  for (int kc = 0; kc < 16; ++kc) {
    bf16x8 a0 = *(const bf16x8*)(Abf + (size_t)(m0 + li) * DD + kc * 32 + qd * 8);
    bf16x8 a1 = *(const bf16x8*)(Abf + (size_t)(m0 + 16 + li) * DD + kc * 32 + qd * 8);
#pragma unroll
    for (int nt = 0; nt < 16; ++nt) {
      bf16x8 b = Wi8[(nt * 16 + kc) * 64 + l];
      acc[0][nt] = __builtin_amdgcn_mfma_f32_16x16x32_bf16(a0, b, acc[0][nt], 0, 0, 0);
      acc[1][nt] = __builtin_amdgcn_mfma_f32_16x16x32_bf16(a1, b, acc[1][nt], 0, 0, 0);
    }
  }
#pragma unroll
  for (int mi = 0; mi < 2; ++mi)
#pragma unroll
    for (int nt = 0; nt < 16; ++nt)
#pragma unroll
      for (int r = 0; r < 4; ++r) {
        int row = m0 + mi * 16 + qd * 4 + r;
        Hbf[(size_t)row * HH + nt * 16 + li] = f2bf(acc[mi][nt][r]);
      }
}

// ---------------------------------------------------------------------------
// Persistent fused decode: 256 blocks x 512 threads; block owns rows 8b..8b+7.
// All 26 steps run inside; zero cross-block communication.
//
// LDS layout (dynamic, 162816 B):
#define LDS_HP    0        // 131072: H_proj bf16 [it=256][j=256], byte ^= (it&7)<<4
#define LDS_XA    131072   //  18432: gates-A chunks [kc=18][lane=64][8bf16], XOR-swz
#define LDS_HL    149504   //   4096: h bf16 [row=8][256], byte ^= (row&7)<<4
#define LDS_HPF   153600   //   8192: hp f32 [8][256]
#define LDS_SE    161792   //   1024: e/alpha f32 [8][32]
#define LDS_TOTAL 162816

// __launch_bounds__(512, 2): 2nd arg = MIN WAVES PER EU -> VGPR budget 512/2 = 256.
// (LDS already caps us at 1 block = 8 waves = 2 waves/SIMD, so nothing is lost.)
__global__ __launch_bounds__(512, 2)
void decode_kernel(
    const unsigned short* __restrict__ bHbf, const unsigned short* __restrict__ Hbf,
    const unsigned short* __restrict__ Wg, const unsigned short* __restrict__ Whb,
    const unsigned short* __restrict__ Wgp, const float* __restrict__ bc,
    const float* __restrict__ b_h2h, const float* __restrict__ W_score,
    const float* __restrict__ b_gen, const int* __restrict__ text,
    float* __restrict__ out) {
  extern __shared__ char lds[];
  char* HP = lds + LDS_HP;
  char* XA = lds + LDS_XA;
  char* HL = lds + LDS_HL;
  float* HPF = (float*)(lds + LDS_HPF);
  float* SE = (float*)(lds + LDS_SE);

  const int tid = threadIdx.x;
  const int w = tid >> 6, ln = tid & 63;
  const int li = ln & 15, qd = ln >> 4;
  const int b0 = blockIdx.x * 8;
  const int hrow = ln & 7;   // MFMA A-frag h-row (rows 8..15 duplicate 0..7, discarded)

  // ---- init: zero XA + HL (contiguous, 22528 B)
  for (int off = tid; off < (18432 + 4096) / 4; off += 512) ((float*)XA)[off] = 0.f;

  // ---- load batch_H slice into registers: wave w = row w, lane ln = d-slice 8*ln..+8
  u32x4 bh[TT];
  {
    const u32x4* src = (const u32x4*)(bHbf + (size_t)(b0 + w) * TT * DD) + ln;
#pragma unroll
    for (int t = 0; t < TT; ++t) bh[t] = src[t * 64];
  }
  // Pin bh in registers: values become asm outputs -> backend cannot
  // rematerialize the global loads inside the step loop.
#pragma unroll
  for (int t = 0; t < TT; ++t) asm volatile("" : "+v"(bh[t]));

  // ---- load H_proj slice into LDS (row-XOR swizzled: byte ^= (it&7)<<4)
  {
    const uint4* src = (const uint4*)(Hbf + (size_t)b0 * TT * HH);
    for (int it8 = 0; it8 < 16; ++it8) {
      int flat = it8 * 512 + tid;
      int it = flat >> 5, j8 = flat & 31;
      uint4 v = src[(size_t)it * 32 + j8];
      *(uint4*)(HP + it * 512 + ((j8 * 16) ^ ((it & 7) << 4))) = v;
    }
  }
  f32x4 cst[2] = {{0.f, 0.f, 0.f, 0.f}, {0.f, 0.f, 0.f, 0.f}};  // c state
  __syncthreads();

  for (int s = 0; s < NSTEP; ++s) {
    // ---- A: hp = h @ W_h2h^T + b_h2h  (16-row M-tile, 8 valid; wave w -> nt 2w..2w+1)
    {
      f32x4 hacc[2] = {{0.f, 0.f, 0.f, 0.f}, {0.f, 0.f, 0.f, 0.f}};
      const bf16x8* WB = (const bf16x8*)Whb;
#pragma unroll
      for (int kc = 0; kc < 8; ++kc) {
        bf16x8 a = *(const bf16x8*)(HL + hrow * 512 + ((kc * 64 + qd * 16) ^ (hrow << 4)));
#pragma unroll
        for (int n = 0; n < 2; ++n) {
          bf16x8 b = WB[((w * 2 + n) * 8 + kc) * 64 + ln];
          hacc[n] = __builtin_amdgcn_mfma_f32_16x16x32_bf16(a, b, hacc[n], 0, 0, 0);
        }
      }
      if (qd < 2) {
#pragma unroll
        for (int n = 0; n < 2; ++n) {
          int col = (w * 2 + n) * 16 + li;
          float bb = b_h2h[col];
#pragma unroll
          for (int r = 0; r < 4; ++r) HPF[(qd * 4 + r) * 256 + col] = hacc[n][r] + bb;
        }
      }
    }
    __syncthreads();

    // ---- B: e[i][t] = sum_j tanh(HP + hp) * ws  (8-lane groups, 4 passes)
    {
      const int sub = ln >> 3, li8 = ln & 7;
#pragma unroll
      for (int p = 0; p < 4; ++p) {
        int pi = p * 64 + w * 8 + sub;       // it = i*32 + t
        int i = pi >> 5, t = pi & 31;
        const char* hpb = HP + pi * 512;
        const int swz = (pi & 7) << 4;
        float v = 0.f;
#pragma unroll
        for (int c = 0; c < 4; ++c) {
          int j = c * 64 + li8 * 8;
          uint4 hv = *(const uint4*)(hpb + ((j * 2) ^ swz));
          float4 hp0 = *(const float4*)(HPF + i * 256 + j);
          float4 hp1 = *(const float4*)(HPF + i * 256 + j + 4);
          float4 ws0 = *(const float4*)(W_score + j);
          float4 ws1 = *(const float4*)(W_score + j + 4);
          v += fast_tanh(bf2f((unsigned short)(hv.x & 0xFFFF)) + hp0.x) * ws0.x;
          v += fast_tanh(bf2f((unsigned short)(hv.x >> 16))    + hp0.y) * ws0.y;
          v += fast_tanh(bf2f((unsigned short)(hv.y & 0xFFFF)) + hp0.z) * ws0.z;
          v += fast_tanh(bf2f((unsigned short)(hv.y >> 16))    + hp0.w) * ws0.w;
          v += fast_tanh(bf2f((unsigned short)(hv.z & 0xFFFF)) + hp1.x) * ws1.x;
          v += fast_tanh(bf2f((unsigned short)(hv.z >> 16))    + hp1.y) * ws1.y;
          v += fast_tanh(bf2f((unsigned short)(hv.w & 0xFFFF)) + hp1.z) * ws1.z;
          v += fast_tanh(bf2f((unsigned short)(hv.w >> 16))    + hp1.w) * ws1.w;
        }
        v += __shfl_xor(v, 1, 64);
        v += __shfl_xor(v, 2, 64);
        v += __shfl_xor(v, 4, 64);
        if (li8 == 0) SE[pi] = v;   // SE[i*32+t]
      }
    }
    __syncthreads();

    // ---- C: softmax over t (32-lane groups)
    if (tid < 256) {
      float e = SE[tid];
      float mx = e;
#pragma unroll
      for (int m = 16; m >= 1; m >>= 1) mx = fmaxf(mx, __shfl_xor(mx, m, 32));
      float pexp = __expf(e - mx);
      float ssum = pexp;
#pragma unroll
      for (int m = 16; m >= 1; m >>= 1) ssum += __shfl_xor(ssum, m, 32);
      SE[tid] = pexp / ssum;
    }
    __syncthreads();

    // ---- D: context from registers -> XA ctx chunks (swizzled); onehot -> kc 16,17
    {
      float acc[8] = {0.f, 0.f, 0.f, 0.f, 0.f, 0.f, 0.f, 0.f};
      const float* al = SE + w * 32;
#pragma unroll
      for (int t = 0; t < TT; ++t) {
        float a = al[t];
        u32x4 hv = bh[t];
        acc[0] += a * bf2f((unsigned short)(hv.x & 0xFFFF));
        acc[1] += a * bf2f((unsigned short)(hv.x >> 16));
        acc[2] += a * bf2f((unsigned short)(hv.y & 0xFFFF));
        acc[3] += a * bf2f((unsigned short)(hv.y >> 16));
        acc[4] += a * bf2f((unsigned short)(hv.z & 0xFFFF));
        acc[5] += a * bf2f((unsigned short)(hv.z >> 16));
        acc[6] += a * bf2f((unsigned short)(hv.w & 0xFFFF));
        acc[7] += a * bf2f((unsigned short)(hv.w >> 16));
      }
      uint4 o = {pk(f2bf(acc[0]), f2bf(acc[1])), pk(f2bf(acc[2]), f2bf(acc[3])),
                 pk(f2bf(acc[4]), f2bf(acc[5])), pk(f2bf(acc[6]), f2bf(acc[7]))};
      int kc = ln >> 2, q = ln & 3;
      int lane_t = q * 16 + w;
      *(uint4*)(XA + kc * 1024 + ((lane_t * 16) ^ ((kc & 7) << 4))) = o;
    }
    if (tid < 64) {
      int row = tid >> 3, sl = tid & 7;
      int kc = 16 + (sl >> 2), q = sl & 3;
      int cc0 = (sl >> 2) * 32 + q * 8;     // onehot class base for this slot
      int ch = text[(b0 + row) * NSTEP + s];
      unsigned short e8[8];
#pragma unroll
      for (int j = 0; j < 8; ++j)
        e8[j] = (cc0 + j == ch) ? (unsigned short)0x3F80 : (unsigned short)0;
      uint4 o = {pk(e8[0], e8[1]), pk(e8[2], e8[3]), pk(e8[4], e8[5]), pk(e8[6], e8[7])};
      int lane_t = q * 16 + row;
      *(uint4*)(XA + kc * 1024 + ((lane_t * 16) ^ ((kc & 7) << 4))) = o;
    }
    __syncthreads();

    // ---- E: gates MFMA (M-tile 16, 8 valid rows; wave w -> nt 8w..8w+7) + cell
    f32x4 acc[8];
#pragma unroll
    for (int n = 0; n < 8; ++n) acc[n] = (f32x4){0.f, 0.f, 0.f, 0.f};
    {
      const bf16x8* W8 = (const bf16x8*)Wg;
      for (int kc = 0; kc < NKC; ++kc) {
        bf16x8 a;
        if (kc < 18) {
          a = *(const bf16x8*)(XA + kc * 1024 + ((ln * 16) ^ ((kc & 7) << 4)));
        } else {
          int kk = (kc - 18) * 64 + qd * 16;
          a = *(const bf16x8*)(HL + hrow * 512 + (kk ^ (hrow << 4)));
        }
#pragma unroll
        for (int n = 0; n < 8; ++n) {
          bf16x8 b = W8[((size_t)(w * 8 + n) * NKC + kc) * 64 + ln];
          acc[n] = __builtin_amdgcn_mfma_f32_16x16x32_bf16(a, b, acc[n], 0, 0, 0);
        }
      }
    }
    unsigned short hreg[2][4];
    if (qd < 2) {
#pragma unroll
      for (int k = 0; k < 2; ++k) {
        int jg = (2 * w + k) * 16 + li;
        float bci = bc[jg], bcf = bc[256 + jg], bcg = bc[512 + jg], bco = bc[768 + jg];
#pragma unroll
        for (int r = 0; r < 4; ++r) {
          float iv = fast_sigmoid(acc[k * 4 + 0][r] + bci);
          float fv = fast_sigmoid(acc[k * 4 + 1][r] + bcf);
          float gv = fast_tanh   (acc[k * 4 + 2][r] + bcg);
          float ov = fast_sigmoid(acc[k * 4 + 3][r] + bco);
          float cn = fv * cst[k][r] + iv * gv;
          cst[k][r] = cn;
          hreg[k][r] = f2bf(ov * fast_tanh(cn));
        }
      }
    }
    __syncthreads();   // all MFMA reads of h(s-1) complete before overwrite

    // ---- F: write h(s) to HL (swizzled)
    if (qd < 2) {
#pragma unroll
      for (int k = 0; k < 2; ++k) {
        int jg = (2 * w + k) * 16 + li;
#pragma unroll
        for (int r = 0; r < 4; ++r) {
          int row = qd * 4 + r;
          *(unsigned short*)(HL + row * 512 + ((jg * 2) ^ (row << 4))) = hreg[k][r];
        }
      }
    }
    __syncthreads();

    // ---- G: probs(s) = h(s) @ W_gen^T + b_gen (waves 0..2; no barrier needed after)
    if (w < 3) {
      f32x4 pa = {0.f, 0.f, 0.f, 0.f};
      const bf16x8* W8 = (const bf16x8*)Wgp;
#pragma unroll
      for (int kc = 0; kc < 8; ++kc) {
        bf16x8 a = *(const bf16x8*)(HL + hrow * 512 + ((kc * 64 + qd * 16) ^ (hrow << 4)));
        bf16x8 b = W8[(w * 8 + kc) * 64 + ln];
        pa = __builtin_amdgcn_mfma_f32_16x16x32_bf16(a, b, pa, 0, 0, 0);
      }
      int col = w * 16 + li;
      if (qd < 2 && col < NCLS) {
        float bg = b_gen[col];
#pragma unroll
        for (int r = 0; r < 4; ++r) {
          int row = qd * 4 + r;
          out[((size_t)(b0 + row) * NSTEP + s) * NCLS + col] = pa[r] + bg;
        }
      }
    }
  }
}

// ---------------------------------------------------------------------------
extern "C" void kernel_launch(void* const* d_in, const int* in_sizes, int n_in,
                              void* d_out, int out_size, void* d_ws, size_t ws_size,
                              hipStream_t stream) {
  const float* batch_H = (const float*)d_in[0];
  const int*   text    = (const int*)d_in[1];
  const float* W_i2h   = (const float*)d_in[2];
  const float* W_h2h   = (const float*)d_in[3];
  const float* b_h2h   = (const float*)d_in[4];
  const float* W_score = (const float*)d_in[5];
  const float* W_ih    = (const float*)d_in[6];
  const float* b_ih    = (const float*)d_in[7];
  const float* W_hh    = (const float*)d_in[8];
  const float* b_hh    = (const float*)d_in[9];
  const float* W_gen   = (const float*)d_in[10];
  const float* b_gen   = (const float*)d_in[11];
  float* out = (float*)d_out;

  // workspace layout (bytes)
  char* p = (char*)d_ws;
  unsigned short* bHbf = (unsigned short*)p;  p += (size_t)2048 * 32 * 512 * 2;  // 64 MiB
  unsigned short* Hbf  = (unsigned short*)p;  p += (size_t)65536 * 256 * 2;      // 32 MiB
  unsigned short* Wg   = (unsigned short*)p;  p += (size_t)64 * NKC * 64 * 8 * 2;
  unsigned short* Wi   = (unsigned short*)p;  p += (size_t)256 * 512 * 2;
  unsigned short* Wgp  = (unsigned short*)p;  p += (size_t)3 * 8 * 64 * 8 * 2;
  unsigned short* Whb  = (unsigned short*)p;  p += (size_t)16 * 8 * 64 * 8 * 2;
  float* bc            = (float*)p;           p += (size_t)1024 * 4;

  static int attr_done = 0;
  if (!attr_done) {
    hipFuncSetAttribute((const void*)decode_kernel,
                        hipFuncAttributeMaxDynamicSharedMemorySize, LDS_TOTAL);
    attr_done = 1;
  }

  cvt_bh_kernel<<<16384, 256, 0, stream>>>(batch_H, bHbf);
  prep_wg_kernel<<<416, 256, 0, stream>>>(W_ih, W_hh, Wg);
  prep_wi_kernel<<<64, 256, 0, stream>>>(W_i2h, Wi);
  prep_wgen_kernel<<<6, 256, 0, stream>>>(W_gen, Wgp);
  prep_whb_bc_kernel<<<32, 256, 0, stream>>>(W_h2h, b_ih, b_hh, Whb, bc);
  hproj_mfma_kernel<<<512, 256, 0, stream>>>(bHbf, Wi, Hbf);
  decode_kernel<<<256, 512, LDS_TOTAL, stream>>>(bHbf, Hbf, Wg, Whb, Wgp, bc,
                                                 b_h2h, W_score, b_gen, text, out);
}

// Round 6
// 4072.207 us; speedup vs baseline: 1.3074x; 1.3065x over previous
//
#include <hip/hip_runtime.h>
#include <cstddef>

// Problem constants
#define TT    32       // T_ENC
#define DD    512      // D_IN
#define HH    256      // hidden
#define NCLS  38       // classes
#define NSTEP 26       // MAXLEN+1
#define NKC   26       // K chunks of 32 for gates GEMM (16 ctx + 2 onehot + 8 h)

typedef float f32x4 __attribute__((ext_vector_type(4)));
typedef short bf16x8 __attribute__((ext_vector_type(8)));
typedef unsigned int u32x4 __attribute__((ext_vector_type(4)));

__device__ __forceinline__ float fast_tanh(float z) {
  float e = __expf(2.f * z);
  return 1.f - 2.f / (e + 1.f);
}
__device__ __forceinline__ float fast_sigmoid(float z) {
  return 1.f / (1.f + __expf(-z));
}
__device__ __forceinline__ float bf2f(unsigned short s) {
  union { unsigned int u; float f; } v; v.u = ((unsigned int)s) << 16; return v.f;
}
__device__ __forceinline__ unsigned short f2bf(float f) {  // RNE
  union { float ff; unsigned int u; } v; v.ff = f;
  unsigned int r = v.u + 0x7FFFu + ((v.u >> 16) & 1u);
  return (unsigned short)(r >> 16);
}
__device__ __forceinline__ unsigned int pk(unsigned short a, unsigned short b) {
  return (unsigned int)a | ((unsigned int)b << 16);
}

// ---------------------------------------------------------------------------
// batch_H fp32 -> bf16 row-major (33,554,432 elems; 8 per thread; grid 16384)
__global__ __launch_bounds__(256) void cvt_bh_kernel(const float* __restrict__ src,
                                                     unsigned short* __restrict__ dst) {
  int t = blockIdx.x * 256 + threadIdx.x;
  const float4* s4 = (const float4*)src + (size_t)t * 2;
  float4 a = s4[0], b = s4[1];
  uint4 o;
  o.x = pk(f2bf(a.x), f2bf(a.y));
  o.y = pk(f2bf(a.z), f2bf(a.w));
  o.z = pk(f2bf(b.x), f2bf(b.y));
  o.w = pk(f2bf(b.z), f2bf(b.w));
  ((uint4*)dst)[t] = o;
}

// gates weights bf16, MFMA-B swizzled [nt(64)][kc(26)][lane][8].
// col = nt*16 + li ; gate = nt&3 ; jg = (nt>>2)*16 + li
__global__ __launch_bounds__(256) void prep_wg_kernel(const float* __restrict__ W_ih,
                                                      const float* __restrict__ W_hh,
                                                      unsigned short* __restrict__ Wg) {
  int flat = blockIdx.x * 256 + threadIdx.x;   // 64*NKC*64 = 106496
  if (flat >= 64 * NKC * 64) return;
  int l = flat & 63, ntkc = flat >> 6;
  int nt = ntkc / NKC, kc = ntkc - nt * NKC;
  int gate = nt & 3;
  int jg = (nt >> 2) * 16 + (l & 15);
  int orig = gate * 256 + jg;
  int kbase = kc * 32 + (l >> 4) * 8;
  unsigned short e[8];
#pragma unroll
  for (int j = 0; j < 8; ++j) {
    int k = kbase + j;
    float v;
    if (k < DD + NCLS)      v = W_ih[orig * (DD + NCLS) + k];
    else if (k < 576)       v = 0.f;                       // pad 550..575
    else                    v = W_hh[orig * HH + (k - 576)];
    e[j] = f2bf(v);
  }
  uint4 o = {pk(e[0], e[1]), pk(e[2], e[3]), pk(e[4], e[5]), pk(e[6], e[7])};
  ((uint4*)Wg)[flat] = o;
}

// W_i2h [256][512] -> bf16 MFMA-B swizzled [nt(16)][kc(16)][lane][8]
__global__ __launch_bounds__(256) void prep_wi_kernel(const float* __restrict__ W_i2h,
                                                      unsigned short* __restrict__ Wi) {
  int flat = blockIdx.x * 256 + threadIdx.x;   // 16*16*64 = 16384
  int l = flat & 63, ntkc = flat >> 6;
  int nt = ntkc >> 4, kc = ntkc & 15;
  int n = nt * 16 + (l & 15);
  int kbase = kc * 32 + (l >> 4) * 8;
  unsigned short e[8];
#pragma unroll
  for (int j = 0; j < 8; ++j) e[j] = f2bf(W_i2h[(size_t)n * DD + kbase + j]);
  uint4 o = {pk(e[0], e[1]), pk(e[2], e[3]), pk(e[4], e[5]), pk(e[6], e[7])};
  ((uint4*)Wi)[flat] = o;
}

// W_gen [38][256] -> bf16 MFMA-B swizzled [nt(3)][kc(8)][lane][8], cols padded to 48
__global__ __launch_bounds__(256) void prep_wgen_kernel(const float* __restrict__ W_gen,
                                                        unsigned short* __restrict__ Wgp) {
  int flat = blockIdx.x * 256 + threadIdx.x;   // 3*8*64 = 1536
  if (flat >= 1536) return;
  int l = flat & 63, ntkc = flat >> 6;
  int nt = ntkc >> 3, kc = ntkc & 7;
  int n = nt * 16 + (l & 15);
  int kbase = kc * 32 + (l >> 4) * 8;
  unsigned short e[8];
#pragma unroll
  for (int j = 0; j < 8; ++j)
    e[j] = (n < NCLS) ? f2bf(W_gen[(size_t)n * HH + kbase + j]) : (unsigned short)0;
  uint4 o = {pk(e[0], e[1]), pk(e[2], e[3]), pk(e[4], e[5]), pk(e[6], e[7])};
  ((uint4*)Wgp)[flat] = o;
}

// W_h2h [256][256] -> bf16 MFMA-B swizzled [nt(16)][kc(8)][lane][8]; plus bc = b_ih+b_hh
__global__ __launch_bounds__(256) void prep_whb_bc_kernel(const float* __restrict__ W_h2h,
                                                          const float* __restrict__ b_ih,
                                                          const float* __restrict__ b_hh,
                                                          unsigned short* __restrict__ Whb,
                                                          float* __restrict__ bc) {
  int flat = blockIdx.x * 256 + threadIdx.x;   // 16*8*64 = 8192
  if (flat >= 8192) return;
  int l = flat & 63, ntkc = flat >> 6;
  int nt = ntkc >> 3, kc = ntkc & 7;
  int n = nt * 16 + (l & 15);
  int kbase = kc * 32 + (l >> 4) * 8;
  unsigned short e[8];
#pragma unroll
  for (int j = 0; j < 8; ++j) e[j] = f2bf(W_h2h[(size_t)n * HH + kbase + j]);
  uint4 o = {pk(e[0], e[1]), pk(e[2], e[3]), pk(e[4], e[5]), pk(e[6], e[7])};
  ((uint4*)Whb)[flat] = o;
  if (flat < 1024) bc[flat] = b_ih[flat] + b_hh[flat];
}

// ---------------------------------------------------------------------------
// H_proj = batch_H(bf16) @ W_i2h^T -> bf16 [65536][256]; 512 blocks * 128 rows
__global__ __launch_bounds__(256) void hproj_mfma_kernel(const unsigned short* __restrict__ Abf,
                                                         const unsigned short* __restrict__ Wi,
                                                         unsigned short* __restrict__ Hbf) {
  const int tid = threadIdx.x;
  const int w = tid >> 6, l = tid & 63;
  const int li = l & 15, qd = l >> 4;
  const int m0 = blockIdx.x * 128 + w * 32;
  f32x4 acc[2][16];
#pragma unroll
  for (int a = 0; a < 2; ++a)
#pragma unroll
    for (int b = 0; b < 16; ++b) acc[a][b] = (f32x4){0.f, 0.f, 0.f, 0.f};
  const bf16x8* Wi8 = (const bf16x8*)Wi;
  for (int kc = 0; kc < 16; ++kc) {
    bf16x8 a0 = *(const bf16x8*)(Abf + (size_t)(m0 + li) * DD + kc * 32 + qd * 8);
    bf16x8 a1 = *(const bf16x8*)(Abf + (size_t)(m0 + 16 + li) * DD + kc * 32 + qd * 8);
#pragma unroll
    for (int nt = 0; nt < 16; ++nt) {
      bf16x8 b = Wi8[(nt * 16 + kc) * 64 + l];
      acc[0][nt] = __builtin_amdgcn_mfma_f32_16x16x32_bf16(a0, b, acc[0][nt], 0, 0, 0);
      acc[1][nt] = __builtin_amdgcn_mfma_f32_16x16x32_bf16(a1, b, acc[1][nt], 0, 0, 0);
    }
  }
#pragma unroll
  for (int mi = 0; mi < 2; ++mi)
#pragma unroll
    for (int nt = 0; nt < 16; ++nt)
#pragma unroll
      for (int r = 0; r < 4; ++r) {
        int row = m0 + mi * 16 + qd * 4 + r;
        Hbf[(size_t)row * HH + nt * 16 + li] = f2bf(acc[mi][nt][r]);
      }
}

// ---------------------------------------------------------------------------
// Persistent fused decode: 256 blocks x 512 threads; block owns rows 8b..8b+7.
// All 26 steps run inside; zero cross-block communication.
// Phase D streams batch_H from global per step (non-temporal, coalesced) instead
// of keeping it register-resident: keeps VGPR demand < 128 (no spill/scratch),
// and nt loads keep the 64 MiB stream out of L2 so Wg (1.7 MiB/XCD) stays hot.
//
// LDS layout (dynamic, 162816 B):
#define LDS_HP    0        // 131072: H_proj bf16 [it=256][j=256], byte ^= (it&7)<<4
#define LDS_XA    131072   //  18432: gates-A chunks [kc=18][lane=64][8bf16], XOR-swz
#define LDS_HL    149504   //   4096: h bf16 [row=8][256], byte ^= (row&7)<<4
#define LDS_HPF   153600   //   8192: hp f32 [8][256]
#define LDS_SE    161792   //   1024: e/alpha f32 [8][32]
#define LDS_TOTAL 162816

__global__ __launch_bounds__(512)
void decode_kernel(
    const unsigned short* __restrict__ bHbf, const unsigned short* __restrict__ Hbf,
    const unsigned short* __restrict__ Wg, const unsigned short* __restrict__ Whb,
    const unsigned short* __restrict__ Wgp, const float* __restrict__ bc,
    const float* __restrict__ b_h2h, const float* __restrict__ W_score,
    const float* __restrict__ b_gen, const int* __restrict__ text,
    float* __restrict__ out) {
  extern __shared__ char lds[];
  char* HP = lds + LDS_HP;
  char* XA = lds + LDS_XA;
  char* HL = lds + LDS_HL;
  float* HPF = (float*)(lds + LDS_HPF);
  float* SE = (float*)(lds + LDS_SE);

  const int tid = threadIdx.x;
  const int w = tid >> 6, ln = tid & 63;
  const int li = ln & 15, qd = ln >> 4;
  const int b0 = blockIdx.x * 8;
  const int hrow = ln & 7;   // MFMA A-frag h-row (rows 8..15 duplicate 0..7, discarded)

  // ---- init: zero XA + HL (contiguous, 22528 B)
  for (int off = tid; off < (18432 + 4096) / 4; off += 512) ((float*)XA)[off] = 0.f;

  // ---- load H_proj slice into LDS (row-XOR swizzled: byte ^= (it&7)<<4)
  {
    const uint4* src = (const uint4*)(Hbf + (size_t)b0 * TT * HH);
    for (int it8 = 0; it8 < 16; ++it8) {
      int flat = it8 * 512 + tid;
      int it = flat >> 5, j8 = flat & 31;
      uint4 v = src[(size_t)it * 32 + j8];
      *(uint4*)(HP + it * 512 + ((j8 * 16) ^ ((it & 7) << 4))) = v;
    }
  }
  f32x4 cst[2] = {{0.f, 0.f, 0.f, 0.f}, {0.f, 0.f, 0.f, 0.f}};  // c state
  __syncthreads();

  // per-wave batch_H row base for phase D streaming
  const u32x4* bhsrc = (const u32x4*)(bHbf + (size_t)(b0 + w) * TT * DD) + ln;

  for (int s = 0; s < NSTEP; ++s) {
    // ---- A: hp = h @ W_h2h^T + b_h2h  (16-row M-tile, 8 valid; wave w -> nt 2w..2w+1)
    {
      f32x4 hacc[2] = {{0.f, 0.f, 0.f, 0.f}, {0.f, 0.f, 0.f, 0.f}};
      const bf16x8* WB = (const bf16x8*)Whb;
#pragma unroll
      for (int kc = 0; kc < 8; ++kc) {
        bf16x8 a = *(const bf16x8*)(HL + hrow * 512 + ((kc * 64 + qd * 16) ^ (hrow << 4)));
#pragma unroll
        for (int n = 0; n < 2; ++n) {
          bf16x8 b = WB[((w * 2 + n) * 8 + kc) * 64 + ln];
          hacc[n] = __builtin_amdgcn_mfma_f32_16x16x32_bf16(a, b, hacc[n], 0, 0, 0);
        }
      }
      if (qd < 2) {
#pragma unroll
        for (int n = 0; n < 2; ++n) {
          int col = (w * 2 + n) * 16 + li;
          float bb = b_h2h[col];
#pragma unroll
          for (int r = 0; r < 4; ++r) HPF[(qd * 4 + r) * 256 + col] = hacc[n][r] + bb;
        }
      }
    }
    __syncthreads();

    // ---- B: e[i][t] = sum_j tanh(HP + hp) * ws  (8-lane groups, 4 passes)
    {
      const int sub = ln >> 3, li8 = ln & 7;
#pragma unroll
      for (int p = 0; p < 4; ++p) {
        int pi = p * 64 + w * 8 + sub;       // it = i*32 + t
        int i = pi >> 5, t = pi & 31;
        const char* hpb = HP + pi * 512;
        const int swz = (pi & 7) << 4;
        float v = 0.f;
#pragma unroll
        for (int c = 0; c < 4; ++c) {
          int j = c * 64 + li8 * 8;
          uint4 hv = *(const uint4*)(hpb + ((j * 2) ^ swz));
          float4 hp0 = *(const float4*)(HPF + i * 256 + j);
          float4 hp1 = *(const float4*)(HPF + i * 256 + j + 4);
          float4 ws0 = *(const float4*)(W_score + j);
          float4 ws1 = *(const float4*)(W_score + j + 4);
          v += fast_tanh(bf2f((unsigned short)(hv.x & 0xFFFF)) + hp0.x) * ws0.x;
          v += fast_tanh(bf2f((unsigned short)(hv.x >> 16))    + hp0.y) * ws0.y;
          v += fast_tanh(bf2f((unsigned short)(hv.y & 0xFFFF)) + hp0.z) * ws0.z;
          v += fast_tanh(bf2f((unsigned short)(hv.y >> 16))    + hp0.w) * ws0.w;
          v += fast_tanh(bf2f((unsigned short)(hv.z & 0xFFFF)) + hp1.x) * ws1.x;
          v += fast_tanh(bf2f((unsigned short)(hv.z >> 16))    + hp1.y) * ws1.y;
          v += fast_tanh(bf2f((unsigned short)(hv.w & 0xFFFF)) + hp1.z) * ws1.z;
          v += fast_tanh(bf2f((unsigned short)(hv.w >> 16))    + hp1.w) * ws1.w;
        }
        v += __shfl_xor(v, 1, 64);
        v += __shfl_xor(v, 2, 64);
        v += __shfl_xor(v, 4, 64);
        if (li8 == 0) SE[pi] = v;   // SE[i*32+t]
      }
    }
    __syncthreads();

    // ---- C: softmax over t (32-lane groups)
    if (tid < 256) {
      float e = SE[tid];
      float mx = e;
#pragma unroll
      for (int m = 16; m >= 1; m >>= 1) mx = fmaxf(mx, __shfl_xor(mx, m, 32));
      float pexp = __expf(e - mx);
      float ssum = pexp;
#pragma unroll
      for (int m = 16; m >= 1; m >>= 1) ssum += __shfl_xor(ssum, m, 32);
      SE[tid] = pexp / ssum;
    }
    __syncthreads();

    // ---- D: context streamed from global (nt loads, 8-deep batches) -> XA (swz)
    {
      float acc[8] = {0.f, 0.f, 0.f, 0.f, 0.f, 0.f, 0.f, 0.f};
      const float* al = SE + w * 32;
#pragma unroll 1
      for (int tb = 0; tb < 4; ++tb) {
        u32x4 hvb[8];
#pragma unroll
        for (int u = 0; u < 8; ++u)
          hvb[u] = __builtin_nontemporal_load(&bhsrc[(tb * 8 + u) * 64]);
#pragma unroll
        for (int u = 0; u < 8; ++u) {
          float a = al[tb * 8 + u];
          u32x4 hv = hvb[u];
          acc[0] += a * bf2f((unsigned short)(hv.x & 0xFFFF));
          acc[1] += a * bf2f((unsigned short)(hv.x >> 16));
          acc[2] += a * bf2f((unsigned short)(hv.y & 0xFFFF));
          acc[3] += a * bf2f((unsigned short)(hv.y >> 16));
          acc[4] += a * bf2f((unsigned short)(hv.z & 0xFFFF));
          acc[5] += a * bf2f((unsigned short)(hv.z >> 16));
          acc[6] += a * bf2f((unsigned short)(hv.w & 0xFFFF));
          acc[7] += a * bf2f((unsigned short)(hv.w >> 16));
        }
      }
      uint4 o = {pk(f2bf(acc[0]), f2bf(acc[1])), pk(f2bf(acc[2]), f2bf(acc[3])),
                 pk(f2bf(acc[4]), f2bf(acc[5])), pk(f2bf(acc[6]), f2bf(acc[7]))};
      int kc = ln >> 2, q = ln & 3;
      int lane_t = q * 16 + w;
      *(uint4*)(XA + kc * 1024 + ((lane_t * 16) ^ ((kc & 7) << 4))) = o;
    }
    if (tid < 64) {
      int row = tid >> 3, sl = tid & 7;
      int kc = 16 + (sl >> 2), q = sl & 3;
      int cc0 = (sl >> 2) * 32 + q * 8;     // onehot class base for this slot
      int ch = text[(b0 + row) * NSTEP + s];
      unsigned short e8[8];
#pragma unroll
      for (int j = 0; j < 8; ++j)
        e8[j] = (cc0 + j == ch) ? (unsigned short)0x3F80 : (unsigned short)0;
      uint4 o = {pk(e8[0], e8[1]), pk(e8[2], e8[3]), pk(e8[4], e8[5]), pk(e8[6], e8[7])};
      int lane_t = q * 16 + row;
      *(uint4*)(XA + kc * 1024 + ((lane_t * 16) ^ ((kc & 7) << 4))) = o;
    }
    __syncthreads();

    // ---- E: gates MFMA (M-tile 16, 8 valid rows; wave w -> nt 8w..8w+7) + cell
    f32x4 acc[8];
#pragma unroll
    for (int n = 0; n < 8; ++n) acc[n] = (f32x4){0.f, 0.f, 0.f, 0.f};
    {
      const bf16x8* W8 = (const bf16x8*)Wg;
      for (int kc = 0; kc < NKC; ++kc) {
        bf16x8 a;
        if (kc < 18) {
          a = *(const bf16x8*)(XA + kc * 1024 + ((ln * 16) ^ ((kc & 7) << 4)));
        } else {
          int kk = (kc - 18) * 64 + qd * 16;
          a = *(const bf16x8*)(HL + hrow * 512 + (kk ^ (hrow << 4)));
        }
#pragma unroll
        for (int n = 0; n < 8; ++n) {
          bf16x8 b = W8[((size_t)(w * 8 + n) * NKC + kc) * 64 + ln];
          acc[n] = __builtin_amdgcn_mfma_f32_16x16x32_bf16(a, b, acc[n], 0, 0, 0);
        }
      }
    }
    unsigned short hreg[2][4];
    if (qd < 2) {
#pragma unroll
      for (int k = 0; k < 2; ++k) {
        int jg = (2 * w + k) * 16 + li;
        float bci = bc[jg], bcf = bc[256 + jg], bcg = bc[512 + jg], bco = bc[768 + jg];
#pragma unroll
        for (int r = 0; r < 4; ++r) {
          float iv = fast_sigmoid(acc[k * 4 + 0][r] + bci);
          float fv = fast_sigmoid(acc[k * 4 + 1][r] + bcf);
          float gv = fast_tanh   (acc[k * 4 + 2][r] + bcg);
          float ov = fast_sigmoid(acc[k * 4 + 3][r] + bco);
          float cn = fv * cst[k][r] + iv * gv;
          cst[k][r] = cn;
          hreg[k][r] = f2bf(ov * fast_tanh(cn));
        }
      }
    }
    __syncthreads();   // all MFMA reads of h(s-1) complete before overwrite

    // ---- F: write h(s) to HL (swizzled)
    if (qd < 2) {
#pragma unroll
      for (int k = 0; k < 2; ++k) {
        int jg = (2 * w + k) * 16 + li;
#pragma unroll
        for (int r = 0; r < 4; ++r) {
          int row = qd * 4 + r;
          *(unsigned short*)(HL + row * 512 + ((jg * 2) ^ (row << 4))) = hreg[k][r];
        }
      }
    }
    __syncthreads();

    // ---- G: probs(s) = h(s) @ W_gen^T + b_gen (waves 0..2; no barrier needed after)
    if (w < 3) {
      f32x4 pa = {0.f, 0.f, 0.f, 0.f};
      const bf16x8* W8 = (const bf16x8*)Wgp;
#pragma unroll
      for (int kc = 0; kc < 8; ++kc) {
        bf16x8 a = *(const bf16x8*)(HL + hrow * 512 + ((kc * 64 + qd * 16) ^ (hrow << 4)));
        bf16x8 b = W8[(w * 8 + kc) * 64 + ln];
        pa = __builtin_amdgcn_mfma_f32_16x16x32_bf16(a, b, pa, 0, 0, 0);
      }
      int col = w * 16 + li;
      if (qd < 2 && col < NCLS) {
        float bg = b_gen[col];
#pragma unroll
        for (int r = 0; r < 4; ++r) {
          int row = qd * 4 + r;
          out[((size_t)(b0 + row) * NSTEP + s) * NCLS + col] = pa[r] + bg;
        }
      }
    }
  }
}

// ---------------------------------------------------------------------------
extern "C" void kernel_launch(void* const* d_in, const int* in_sizes, int n_in,
                              void* d_out, int out_size, void* d_ws, size_t ws_size,
                              hipStream_t stream) {
  const float* batch_H = (const float*)d_in[0];
  const int*   text    = (const int*)d_in[1];
  const float* W_i2h   = (const float*)d_in[2];
  const float* W_h2h   = (const float*)d_in[3];
  const float* b_h2h   = (const float*)d_in[4];
  const float* W_score = (const float*)d_in[5];
  const float* W_ih    = (const float*)d_in[6];
  const float* b_ih    = (const float*)d_in[7];
  const float* W_hh    = (const float*)d_in[8];
  const float* b_hh    = (const float*)d_in[9];
  const float* W_gen   = (const float*)d_in[10];
  const float* b_gen   = (const float*)d_in[11];
  float* out = (float*)d_out;

  // workspace layout (bytes)
  char* p = (char*)d_ws;
  unsigned short* bHbf = (unsigned short*)p;  p += (size_t)2048 * 32 * 512 * 2;  // 64 MiB
  unsigned short* Hbf  = (unsigned short*)p;  p += (size_t)65536 * 256 * 2;      // 32 MiB
  unsigned short* Wg   = (unsigned short*)p;  p += (size_t)64 * NKC * 64 * 8 * 2;
  unsigned short* Wi   = (unsigned short*)p;  p += (size_t)256 * 512 * 2;
  unsigned short* Wgp  = (unsigned short*)p;  p += (size_t)3 * 8 * 64 * 8 * 2;
  unsigned short* Whb  = (unsigned short*)p;  p += (size_t)16 * 8 * 64 * 8 * 2;
  float* bc            = (float*)p;           p += (size_t)1024 * 4;

  static int attr_done = 0;
  if (!attr_done) {
    hipFuncSetAttribute((const void*)decode_kernel,
                        hipFuncAttributeMaxDynamicSharedMemorySize, LDS_TOTAL);
    attr_done = 1;
  }

  cvt_bh_kernel<<<16384, 256, 0, stream>>>(batch_H, bHbf);
  prep_wg_kernel<<<416, 256, 0, stream>>>(W_ih, W_hh, Wg);
  prep_wi_kernel<<<64, 256, 0, stream>>>(W_i2h, Wi);
  prep_wgen_kernel<<<6, 256, 0, stream>>>(W_gen, Wgp);
  prep_whb_bc_kernel<<<32, 256, 0, stream>>>(W_h2h, b_ih, b_hh, Whb, bc);
  hproj_mfma_kernel<<<512, 256, 0, stream>>>(bHbf, Wi, Hbf);
  decode_kernel<<<256, 512, LDS_TOTAL, stream>>>(bHbf, Hbf, Wg, Whb, Wgp, bc,
                                                 b_h2h, W_score, b_gen, text, out);
}

// Round 7
// 2879.527 us; speedup vs baseline: 1.8489x; 1.4142x over previous
//
#include <hip/hip_runtime.h>
#include <cstddef>

// Problem constants
#define TT    32       // T_ENC
#define DD    512      // D_IN
#define HH    256      // hidden
#define NCLS  38       // classes
#define NSTEP 26       // MAXLEN+1
#define NKC   26       // K chunks of 32 for gates GEMM (16 ctx + 2 onehot + 8 h)

typedef float f32x4 __attribute__((ext_vector_type(4)));
typedef short bf16x8 __attribute__((ext_vector_type(8)));
typedef unsigned int u32x4 __attribute__((ext_vector_type(4)));

__device__ __forceinline__ float fast_tanh(float z) {
  float e = __expf(2.f * z);
  return 1.f - 2.f / (e + 1.f);
}
__device__ __forceinline__ float fast_sigmoid(float z) {
  return 1.f / (1.f + __expf(-z));
}
__device__ __forceinline__ float bf2f(unsigned short s) {
  union { unsigned int u; float f; } v; v.u = ((unsigned int)s) << 16; return v.f;
}
__device__ __forceinline__ unsigned short f2bf(float f) {  // RNE
  union { float ff; unsigned int u; } v; v.ff = f;
  unsigned int r = v.u + 0x7FFFu + ((v.u >> 16) & 1u);
  return (unsigned short)(r >> 16);
}
__device__ __forceinline__ unsigned int pk(unsigned short a, unsigned short b) {
  return (unsigned int)a | ((unsigned int)b << 16);
}

// ---------------------------------------------------------------------------
// batch_H fp32 -> bf16 row-major (33,554,432 elems; 8 per thread; grid 16384)
__global__ __launch_bounds__(256) void cvt_bh_kernel(const float* __restrict__ src,
                                                     unsigned short* __restrict__ dst) {
  int t = blockIdx.x * 256 + threadIdx.x;
  const float4* s4 = (const float4*)src + (size_t)t * 2;
  float4 a = s4[0], b = s4[1];
  uint4 o;
  o.x = pk(f2bf(a.x), f2bf(a.y));
  o.y = pk(f2bf(a.z), f2bf(a.w));
  o.z = pk(f2bf(b.x), f2bf(b.y));
  o.w = pk(f2bf(b.z), f2bf(b.w));
  ((uint4*)dst)[t] = o;
}

// gates weights bf16, MFMA-B swizzled [nt(64)][kc(26)][lane][8].
// col = nt*16 + li ; gate = nt&3 ; jg = (nt>>2)*16 + li
__global__ __launch_bounds__(256) void prep_wg_kernel(const float* __restrict__ W_ih,
                                                      const float* __restrict__ W_hh,
                                                      unsigned short* __restrict__ Wg) {
  int flat = blockIdx.x * 256 + threadIdx.x;   // 64*NKC*64 = 106496
  if (flat >= 64 * NKC * 64) return;
  int l = flat & 63, ntkc = flat >> 6;
  int nt = ntkc / NKC, kc = ntkc - nt * NKC;
  int gate = nt & 3;
  int jg = (nt >> 2) * 16 + (l & 15);
  int orig = gate * 256 + jg;
  int kbase = kc * 32 + (l >> 4) * 8;
  unsigned short e[8];
#pragma unroll
  for (int j = 0; j < 8; ++j) {
    int k = kbase + j;
    float v;
    if (k < DD + NCLS)      v = W_ih[orig * (DD + NCLS) + k];
    else if (k < 576)       v = 0.f;                       // pad 550..575
    else                    v = W_hh[orig * HH + (k - 576)];
    e[j] = f2bf(v);
  }
  uint4 o = {pk(e[0], e[1]), pk(e[2], e[3]), pk(e[4], e[5]), pk(e[6], e[7])};
  ((uint4*)Wg)[flat] = o;
}

// W_i2h [256][512] -> bf16 MFMA-B swizzled [nt(16)][kc(16)][lane][8]
__global__ __launch_bounds__(256) void prep_wi_kernel(const float* __restrict__ W_i2h,
                                                      unsigned short* __restrict__ Wi) {
  int flat = blockIdx.x * 256 + threadIdx.x;   // 16*16*64 = 16384
  int l = flat & 63, ntkc = flat >> 6;
  int nt = ntkc >> 4, kc = ntkc & 15;
  int n = nt * 16 + (l & 15);
  int kbase = kc * 32 + (l >> 4) * 8;
  unsigned short e[8];
#pragma unroll
  for (int j = 0; j < 8; ++j) e[j] = f2bf(W_i2h[(size_t)n * DD + kbase + j]);
  uint4 o = {pk(e[0], e[1]), pk(e[2], e[3]), pk(e[4], e[5]), pk(e[6], e[7])};
  ((uint4*)Wi)[flat] = o;
}

// W_gen [38][256] -> bf16 MFMA-B swizzled [nt(3)][kc(8)][lane][8], cols padded to 48
__global__ __launch_bounds__(256) void prep_wgen_kernel(const float* __restrict__ W_gen,
                                                        unsigned short* __restrict__ Wgp) {
  int flat = blockIdx.x * 256 + threadIdx.x;   // 3*8*64 = 1536
  if (flat >= 1536) return;
  int l = flat & 63, ntkc = flat >> 6;
  int nt = ntkc >> 3, kc = ntkc & 7;
  int n = nt * 16 + (l & 15);
  int kbase = kc * 32 + (l >> 4) * 8;
  unsigned short e[8];
#pragma unroll
  for (int j = 0; j < 8; ++j)
    e[j] = (n < NCLS) ? f2bf(W_gen[(size_t)n * HH + kbase + j]) : (unsigned short)0;
  uint4 o = {pk(e[0], e[1]), pk(e[2], e[3]), pk(e[4], e[5]), pk(e[6], e[7])};
  ((uint4*)Wgp)[flat] = o;
}

// W_h2h [256][256] -> bf16 MFMA-B swizzled [nt(16)][kc(8)][lane][8]; plus bc = b_ih+b_hh
__global__ __launch_bounds__(256) void prep_whb_bc_kernel(const float* __restrict__ W_h2h,
                                                          const float* __restrict__ b_ih,
                                                          const float* __restrict__ b_hh,
                                                          unsigned short* __restrict__ Whb,
                                                          float* __restrict__ bc) {
  int flat = blockIdx.x * 256 + threadIdx.x;   // 16*8*64 = 8192
  if (flat >= 8192) return;
  int l = flat & 63, ntkc = flat >> 6;
  int nt = ntkc >> 3, kc = ntkc & 7;
  int n = nt * 16 + (l & 15);
  int kbase = kc * 32 + (l >> 4) * 8;
  unsigned short e[8];
#pragma unroll
  for (int j = 0; j < 8; ++j) e[j] = f2bf(W_h2h[(size_t)n * HH + kbase + j]);
  uint4 o = {pk(e[0], e[1]), pk(e[2], e[3]), pk(e[4], e[5]), pk(e[6], e[7])};
  ((uint4*)Whb)[flat] = o;
  if (flat < 1024) bc[flat] = b_ih[flat] + b_hh[flat];
}

// ---------------------------------------------------------------------------
// H_proj = batch_H(bf16) @ W_i2h^T -> bf16 [65536][256]; 512 blocks * 128 rows
__global__ __launch_bounds__(256) void hproj_mfma_kernel(const unsigned short* __restrict__ Abf,
                                                         const unsigned short* __restrict__ Wi,
                                                         unsigned short* __restrict__ Hbf) {
  const int tid = threadIdx.x;
  const int w = tid >> 6, l = tid & 63;
  const int li = l & 15, qd = l >> 4;
  const int m0 = blockIdx.x * 128 + w * 32;
  f32x4 acc[2][16];
#pragma unroll
  for (int a = 0; a < 2; ++a)
#pragma unroll
    for (int b = 0; b < 16; ++b) acc[a][b] = (f32x4){0.f, 0.f, 0.f, 0.f};
  const bf16x8* Wi8 = (const bf16x8*)Wi;
  for (int kc = 0; kc < 16; ++kc) {
    bf16x8 a0 = *(const bf16x8*)(Abf + (size_t)(m0 + li) * DD + kc * 32 + qd * 8);
    bf16x8 a1 = *(const bf16x8*)(Abf + (size_t)(m0 + 16 + li) * DD + kc * 32 + qd * 8);
#pragma unroll
    for (int nt = 0; nt < 16; ++nt) {
      bf16x8 b = Wi8[(nt * 16 + kc) * 64 + l];
      acc[0][nt] = __builtin_amdgcn_mfma_f32_16x16x32_bf16(a0, b, acc[0][nt], 0, 0, 0);
      acc[1][nt] = __builtin_amdgcn_mfma_f32_16x16x32_bf16(a1, b, acc[1][nt], 0, 0, 0);
    }
  }
#pragma unroll
  for (int mi = 0; mi < 2; ++mi)
#pragma unroll
    for (int nt = 0; nt < 16; ++nt)
#pragma unroll
      for (int r = 0; r < 4; ++r) {
        int row = m0 + mi * 16 + qd * 4 + r;
        Hbf[(size_t)row * HH + nt * 16 + li] = f2bf(acc[mi][nt][r]);
      }
}

// ---------------------------------------------------------------------------
// Persistent fused decode: 256 blocks x 512 threads; block owns rows 8b..8b+7.
// All 26 steps run inside; zero cross-block communication.
// Phase D streams batch_H from global per step with sc1 (system-scope) loads:
// bypasses the per-XCD L2 so the 8 MB/step stream cannot evict Wg (1.7 MiB),
// which must stay L2-resident for phase E.
//
// LDS layout (dynamic, 162816 B):
#define LDS_HP    0        // 131072: H_proj bf16 [it=256][j=256], byte ^= (it&7)<<4
#define LDS_XA    131072   //  18432: gates-A chunks [kc=18][lane=64][8bf16], XOR-swz
#define LDS_HL    149504   //   4096: h bf16 [row=8][256], byte ^= (row&7)<<4
#define LDS_HPF   153600   //   8192: hp f32 [8][256]
#define LDS_SE    161792   //   1024: e/alpha f32 [8][32]
#define LDS_TOTAL 162816

__global__ __launch_bounds__(512)
void decode_kernel(
    const unsigned short* __restrict__ bHbf, const unsigned short* __restrict__ Hbf,
    const unsigned short* __restrict__ Wg, const unsigned short* __restrict__ Whb,
    const unsigned short* __restrict__ Wgp, const float* __restrict__ bc,
    const float* __restrict__ b_h2h, const float* __restrict__ W_score,
    const float* __restrict__ b_gen, const int* __restrict__ text,
    float* __restrict__ out) {
  extern __shared__ char lds[];
  char* HP = lds + LDS_HP;
  char* XA = lds + LDS_XA;
  char* HL = lds + LDS_HL;
  float* HPF = (float*)(lds + LDS_HPF);
  float* SE = (float*)(lds + LDS_SE);

  const int tid = threadIdx.x;
  const int w = tid >> 6, ln = tid & 63;
  const int li = ln & 15, qd = ln >> 4;
  const int b0 = blockIdx.x * 8;
  const int hrow = ln & 7;   // MFMA A-frag h-row (rows 8..15 duplicate 0..7, discarded)

  // ---- init: zero XA + HL (contiguous, 22528 B)
  for (int off = tid; off < (18432 + 4096) / 4; off += 512) ((float*)XA)[off] = 0.f;

  // ---- load H_proj slice into LDS (row-XOR swizzled: byte ^= (it&7)<<4)
  {
    const uint4* src = (const uint4*)(Hbf + (size_t)b0 * TT * HH);
    for (int it8 = 0; it8 < 16; ++it8) {
      int flat = it8 * 512 + tid;
      int it = flat >> 5, j8 = flat & 31;
      uint4 v = src[(size_t)it * 32 + j8];
      *(uint4*)(HP + it * 512 + ((j8 * 16) ^ ((it & 7) << 4))) = v;
    }
  }
  f32x4 cst[2] = {{0.f, 0.f, 0.f, 0.f}, {0.f, 0.f, 0.f, 0.f}};  // c state
  __syncthreads();

  // per-wave batch_H row base for phase D streaming
  const u32x4* bhsrc = (const u32x4*)(bHbf + (size_t)(b0 + w) * TT * DD) + ln;

  for (int s = 0; s < NSTEP; ++s) {
    // ---- A: hp = h @ W_h2h^T + b_h2h  (16-row M-tile, 8 valid; wave w -> nt 2w..2w+1)
    {
      f32x4 hacc[2] = {{0.f, 0.f, 0.f, 0.f}, {0.f, 0.f, 0.f, 0.f}};
      const bf16x8* WB = (const bf16x8*)Whb;
#pragma unroll
      for (int kc = 0; kc < 8; ++kc) {
        bf16x8 a = *(const bf16x8*)(HL + hrow * 512 + ((kc * 64 + qd * 16) ^ (hrow << 4)));
#pragma unroll
        for (int n = 0; n < 2; ++n) {
          bf16x8 b = WB[((w * 2 + n) * 8 + kc) * 64 + ln];
          hacc[n] = __builtin_amdgcn_mfma_f32_16x16x32_bf16(a, b, hacc[n], 0, 0, 0);
        }
      }
      if (qd < 2) {
#pragma unroll
        for (int n = 0; n < 2; ++n) {
          int col = (w * 2 + n) * 16 + li;
          float bb = b_h2h[col];
#pragma unroll
          for (int r = 0; r < 4; ++r) HPF[(qd * 4 + r) * 256 + col] = hacc[n][r] + bb;
        }
      }
    }
    __syncthreads();

    // ---- B: e[i][t] = sum_j tanh(HP + hp) * ws  (8-lane groups, 4 passes)
    {
      const int sub = ln >> 3, li8 = ln & 7;
#pragma unroll
      for (int p = 0; p < 4; ++p) {
        int pi = p * 64 + w * 8 + sub;       // it = i*32 + t
        int i = pi >> 5, t = pi & 31;
        const char* hpb = HP + pi * 512;
        const int swz = (pi & 7) << 4;
        float v = 0.f;
#pragma unroll
        for (int c = 0; c < 4; ++c) {
          int j = c * 64 + li8 * 8;
          uint4 hv = *(const uint4*)(hpb + ((j * 2) ^ swz));
          float4 hp0 = *(const float4*)(HPF + i * 256 + j);
          float4 hp1 = *(const float4*)(HPF + i * 256 + j + 4);
          float4 ws0 = *(const float4*)(W_score + j);
          float4 ws1 = *(const float4*)(W_score + j + 4);
          v += fast_tanh(bf2f((unsigned short)(hv.x & 0xFFFF)) + hp0.x) * ws0.x;
          v += fast_tanh(bf2f((unsigned short)(hv.x >> 16))    + hp0.y) * ws0.y;
          v += fast_tanh(bf2f((unsigned short)(hv.y & 0xFFFF)) + hp0.z) * ws0.z;
          v += fast_tanh(bf2f((unsigned short)(hv.y >> 16))    + hp0.w) * ws0.w;
          v += fast_tanh(bf2f((unsigned short)(hv.z & 0xFFFF)) + hp1.x) * ws1.x;
          v += fast_tanh(bf2f((unsigned short)(hv.z >> 16))    + hp1.y) * ws1.y;
          v += fast_tanh(bf2f((unsigned short)(hv.w & 0xFFFF)) + hp1.z) * ws1.z;
          v += fast_tanh(bf2f((unsigned short)(hv.w >> 16))    + hp1.w) * ws1.w;
        }
        v += __shfl_xor(v, 1, 64);
        v += __shfl_xor(v, 2, 64);
        v += __shfl_xor(v, 4, 64);
        if (li8 == 0) SE[pi] = v;   // SE[i*32+t]
      }
    }
    __syncthreads();

    // ---- C: softmax over t (32-lane groups)
    if (tid < 256) {
      float e = SE[tid];
      float mx = e;
#pragma unroll
      for (int m = 16; m >= 1; m >>= 1) mx = fmaxf(mx, __shfl_xor(mx, m, 32));
      float pexp = __expf(e - mx);
      float ssum = pexp;
#pragma unroll
      for (int m = 16; m >= 1; m >>= 1) ssum += __shfl_xor(ssum, m, 32);
      SE[tid] = pexp / ssum;
    }
    __syncthreads();

    // ---- D: context streamed from global with sc1 (L2-bypass) loads -> XA (swz)
    {
      float acc[8] = {0.f, 0.f, 0.f, 0.f, 0.f, 0.f, 0.f, 0.f};
      const float* al = SE + w * 32;
#pragma unroll 1
      for (int tb = 0; tb < 8; ++tb) {
        const u32x4* p0 = &bhsrc[(tb * 4 + 0) * 64];
        const u32x4* p1 = &bhsrc[(tb * 4 + 1) * 64];
        const u32x4* p2 = &bhsrc[(tb * 4 + 2) * 64];
        const u32x4* p3 = &bhsrc[(tb * 4 + 3) * 64];
        u32x4 h0, h1, h2, h3;
        asm volatile(
            "global_load_dwordx4 %0, %4, off sc1 nt\n\t"
            "global_load_dwordx4 %1, %5, off sc1 nt\n\t"
            "global_load_dwordx4 %2, %6, off sc1 nt\n\t"
            "global_load_dwordx4 %3, %7, off sc1 nt\n\t"
            "s_waitcnt vmcnt(0)"
            : "=&v"(h0), "=&v"(h1), "=&v"(h2), "=&v"(h3)
            : "v"(p0), "v"(p1), "v"(p2), "v"(p3));
        u32x4 hvb[4] = {h0, h1, h2, h3};
#pragma unroll
        for (int u = 0; u < 4; ++u) {
          float a = al[tb * 4 + u];
          u32x4 hv = hvb[u];
          acc[0] += a * bf2f((unsigned short)(hv.x & 0xFFFF));
          acc[1] += a * bf2f((unsigned short)(hv.x >> 16));
          acc[2] += a * bf2f((unsigned short)(hv.y & 0xFFFF));
          acc[3] += a * bf2f((unsigned short)(hv.y >> 16));
          acc[4] += a * bf2f((unsigned short)(hv.z & 0xFFFF));
          acc[5] += a * bf2f((unsigned short)(hv.z >> 16));
          acc[6] += a * bf2f((unsigned short)(hv.w & 0xFFFF));
          acc[7] += a * bf2f((unsigned short)(hv.w >> 16));
        }
      }
      uint4 o = {pk(f2bf(acc[0]), f2bf(acc[1])), pk(f2bf(acc[2]), f2bf(acc[3])),
                 pk(f2bf(acc[4]), f2bf(acc[5])), pk(f2bf(acc[6]), f2bf(acc[7]))};
      int kc = ln >> 2, q = ln & 3;
      int lane_t = q * 16 + w;
      *(uint4*)(XA + kc * 1024 + ((lane_t * 16) ^ ((kc & 7) << 4))) = o;
    }
    if (tid < 64) {
      int row = tid >> 3, sl = tid & 7;
      int kc = 16 + (sl >> 2), q = sl & 3;
      int cc0 = (sl >> 2) * 32 + q * 8;     // onehot class base for this slot
      int ch = text[(b0 + row) * NSTEP + s];
      unsigned short e8[8];
#pragma unroll
      for (int j = 0; j < 8; ++j)
        e8[j] = (cc0 + j == ch) ? (unsigned short)0x3F80 : (unsigned short)0;
      uint4 o = {pk(e8[0], e8[1]), pk(e8[2], e8[3]), pk(e8[4], e8[5]), pk(e8[6], e8[7])};
      int lane_t = q * 16 + row;
      *(uint4*)(XA + kc * 1024 + ((lane_t * 16) ^ ((kc & 7) << 4))) = o;
    }
    __syncthreads();

    // ---- E: gates MFMA (M-tile 16, 8 valid rows; wave w -> nt 8w..8w+7) + cell
    f32x4 acc[8];
#pragma unroll
    for (int n = 0; n < 8; ++n) acc[n] = (f32x4){0.f, 0.f, 0.f, 0.f};
    {
      const bf16x8* W8 = (const bf16x8*)Wg;
      for (int kc = 0; kc < NKC; ++kc) {
        bf16x8 a;
        if (kc < 18) {
          a = *(const bf16x8*)(XA + kc * 1024 + ((ln * 16) ^ ((kc & 7) << 4)));
        } else {
          int kk = (kc - 18) * 64 + qd * 16;
          a = *(const bf16x8*)(HL + hrow * 512 + (kk ^ (hrow << 4)));
        }
#pragma unroll
        for (int n = 0; n < 8; ++n) {
          bf16x8 b = W8[((size_t)(w * 8 + n) * NKC + kc) * 64 + ln];
          acc[n] = __builtin_amdgcn_mfma_f32_16x16x32_bf16(a, b, acc[n], 0, 0, 0);
        }
      }
    }
    unsigned short hreg[2][4];
    if (qd < 2) {
#pragma unroll
      for (int k = 0; k < 2; ++k) {
        int jg = (2 * w + k) * 16 + li;
        float bci = bc[jg], bcf = bc[256 + jg], bcg = bc[512 + jg], bco = bc[768 + jg];
#pragma unroll
        for (int r = 0; r < 4; ++r) {
          float iv = fast_sigmoid(acc[k * 4 + 0][r] + bci);
          float fv = fast_sigmoid(acc[k * 4 + 1][r] + bcf);
          float gv = fast_tanh   (acc[k * 4 + 2][r] + bcg);
          float ov = fast_sigmoid(acc[k * 4 + 3][r] + bco);
          float cn = fv * cst[k][r] + iv * gv;
          cst[k][r] = cn;
          hreg[k][r] = f2bf(ov * fast_tanh(cn));
        }
      }
    }
    __syncthreads();   // all MFMA reads of h(s-1) complete before overwrite

    // ---- F: write h(s) to HL (swizzled)
    if (qd < 2) {
#pragma unroll
      for (int k = 0; k < 2; ++k) {
        int jg = (2 * w + k) * 16 + li;
#pragma unroll
        for (int r = 0; r < 4; ++r) {
          int row = qd * 4 + r;
          *(unsigned short*)(HL + row * 512 + ((jg * 2) ^ (row << 4))) = hreg[k][r];
        }
      }
    }
    __syncthreads();

    // ---- G: probs(s) = h(s) @ W_gen^T + b_gen (waves 0..2; no barrier needed after)
    if (w < 3) {
      f32x4 pa = {0.f, 0.f, 0.f, 0.f};
      const bf16x8* W8 = (const bf16x8*)Wgp;
#pragma unroll
      for (int kc = 0; kc < 8; ++kc) {
        bf16x8 a = *(const bf16x8*)(HL + hrow * 512 + ((kc * 64 + qd * 16) ^ (hrow << 4)));
        bf16x8 b = W8[(w * 8 + kc) * 64 + ln];
        pa = __builtin_amdgcn_mfma_f32_16x16x32_bf16(a, b, pa, 0, 0, 0);
      }
      int col = w * 16 + li;
      if (qd < 2 && col < NCLS) {
        float bg = b_gen[col];
#pragma unroll
        for (int r = 0; r < 4; ++r) {
          int row = qd * 4 + r;
          out[((size_t)(b0 + row) * NSTEP + s) * NCLS + col] = pa[r] + bg;
        }
      }
    }
  }
}

// ---------------------------------------------------------------------------
extern "C" void kernel_launch(void* const* d_in, const int* in_sizes, int n_in,
                              void* d_out, int out_size, void* d_ws, size_t ws_size,
                              hipStream_t stream) {
  const float* batch_H = (const float*)d_in[0];
  const int*   text    = (const int*)d_in[1];
  const float* W_i2h   = (const float*)d_in[2];
  const float* W_h2h   = (const float*)d_in[3];
  const float* b_h2h   = (const float*)d_in[4];
  const float* W_score = (const float*)d_in[5];
  const float* W_ih    = (const float*)d_in[6];
  const float* b_ih    = (const float*)d_in[7];
  const float* W_hh    = (const float*)d_in[8];
  const float* b_hh    = (const float*)d_in[9];
  const float* W_gen   = (const float*)d_in[10];
  const float* b_gen   = (const float*)d_in[11];
  float* out = (float*)d_out;

  // workspace layout (bytes)
  char* p = (char*)d_ws;
  unsigned short* bHbf = (unsigned short*)p;  p += (size_t)2048 * 32 * 512 * 2;  // 64 MiB
  unsigned short* Hbf  = (unsigned short*)p;  p += (size_t)65536 * 256 * 2;      // 32 MiB
  unsigned short* Wg   = (unsigned short*)p;  p += (size_t)64 * NKC * 64 * 8 * 2;
  unsigned short* Wi   = (unsigned short*)p;  p += (size_t)256 * 512 * 2;
  unsigned short* Wgp  = (unsigned short*)p;  p += (size_t)3 * 8 * 64 * 8 * 2;
  unsigned short* Whb  = (unsigned short*)p;  p += (size_t)16 * 8 * 64 * 8 * 2;
  float* bc            = (float*)p;           p += (size_t)1024 * 4;

  static int attr_done = 0;
  if (!attr_done) {
    hipFuncSetAttribute((const void*)decode_kernel,
                        hipFuncAttributeMaxDynamicSharedMemorySize, LDS_TOTAL);
    attr_done = 1;
  }

  cvt_bh_kernel<<<16384, 256, 0, stream>>>(batch_H, bHbf);
  prep_wg_kernel<<<416, 256, 0, stream>>>(W_ih, W_hh, Wg);
  prep_wi_kernel<<<64, 256, 0, stream>>>(W_i2h, Wi);
  prep_wgen_kernel<<<6, 256, 0, stream>>>(W_gen, Wgp);
  prep_whb_bc_kernel<<<32, 256, 0, stream>>>(W_h2h, b_ih, b_hh, Whb, bc);
  hproj_mfma_kernel<<<512, 256, 0, stream>>>(bHbf, Wi, Hbf);
  decode_kernel<<<256, 512, LDS_TOTAL, stream>>>(bHbf, Hbf, Wg, Whb, Wgp, bc,
                                                 b_h2h, W_score, b_gen, text, out);
}

// Round 8
// 1458.967 us; speedup vs baseline: 3.6491x; 1.9737x over previous
//
#include <hip/hip_runtime.h>
#include <cstddef>

// Problem constants
#define TT    32       // T_ENC
#define DD    512      // D_IN
#define HH    256      // hidden
#define NCLS  38       // classes
#define NSTEP 26       // MAXLEN+1
#define NKC   26       // K chunks of 32 for gates GEMM (16 ctx + 2 onehot + 8 h)

typedef float f32x4 __attribute__((ext_vector_type(4)));
typedef short bf16x8 __attribute__((ext_vector_type(8)));
typedef unsigned int u32x4 __attribute__((ext_vector_type(4)));

__device__ __forceinline__ float fast_tanh(float z) {
  float e = __expf(2.f * z);
  return 1.f - 2.f / (e + 1.f);
}
__device__ __forceinline__ float fast_sigmoid(float z) {
  return 1.f / (1.f + __expf(-z));
}
__device__ __forceinline__ float bf2f(unsigned short s) {
  union { unsigned int u; float f; } v; v.u = ((unsigned int)s) << 16; return v.f;
}
__device__ __forceinline__ unsigned short f2bf(float f) {  // RNE
  union { float ff; unsigned int u; } v; v.ff = f;
  unsigned int r = v.u + 0x7FFFu + ((v.u >> 16) & 1u);
  return (unsigned short)(r >> 16);
}
__device__ __forceinline__ unsigned int pk(unsigned short a, unsigned short b) {
  return (unsigned int)a | ((unsigned int)b << 16);
}

// async global->LDS 16B copy (DMA; dest must be wave-uniform base + lane*16)
__device__ __forceinline__ void stage16(const void* g, void* l) {
  __builtin_amdgcn_global_load_lds(
      (const __attribute__((address_space(1))) unsigned int*)g,
      (__attribute__((address_space(3))) unsigned int*)l, 16, 0, 0);
}

// ---------------------------------------------------------------------------
// batch_H fp32 -> bf16 row-major (33,554,432 elems; 8 per thread; grid 16384)
__global__ __launch_bounds__(256) void cvt_bh_kernel(const float* __restrict__ src,
                                                     unsigned short* __restrict__ dst) {
  int t = blockIdx.x * 256 + threadIdx.x;
  const float4* s4 = (const float4*)src + (size_t)t * 2;
  float4 a = s4[0], b = s4[1];
  uint4 o;
  o.x = pk(f2bf(a.x), f2bf(a.y));
  o.y = pk(f2bf(a.z), f2bf(a.w));
  o.z = pk(f2bf(b.x), f2bf(b.y));
  o.w = pk(f2bf(b.z), f2bf(b.w));
  ((uint4*)dst)[t] = o;
}

// gates weights bf16, MFMA-B swizzled, kc-major: [kc(26)][nt(64)][lane][8].
// col = nt*16 + li ; gate = nt&3 ; jg = (nt>>2)*16 + li
__global__ __launch_bounds__(256) void prep_wg_kernel(const float* __restrict__ W_ih,
                                                      const float* __restrict__ W_hh,
                                                      unsigned short* __restrict__ Wg) {
  int flat = blockIdx.x * 256 + threadIdx.x;   // 26*64*64 = 106496
  if (flat >= 64 * NKC * 64) return;
  int l = flat & 63, ntkc = flat >> 6;
  int kc = ntkc >> 6;          // 0..25  (kc-major!)
  int nt = ntkc & 63;
  int gate = nt & 3;
  int jg = (nt >> 2) * 16 + (l & 15);
  int orig = gate * 256 + jg;
  int kbase = kc * 32 + (l >> 4) * 8;
  unsigned short e[8];
#pragma unroll
  for (int j = 0; j < 8; ++j) {
    int k = kbase + j;
    float v;
    if (k < DD + NCLS)      v = W_ih[orig * (DD + NCLS) + k];
    else if (k < 576)       v = 0.f;                       // pad 550..575
    else                    v = W_hh[orig * HH + (k - 576)];
    e[j] = f2bf(v);
  }
  uint4 o = {pk(e[0], e[1]), pk(e[2], e[3]), pk(e[4], e[5]), pk(e[6], e[7])};
  ((uint4*)Wg)[flat] = o;
}

// W_i2h [256][512] -> bf16 MFMA-B swizzled [nt(16)][kc(16)][lane][8]
__global__ __launch_bounds__(256) void prep_wi_kernel(const float* __restrict__ W_i2h,
                                                      unsigned short* __restrict__ Wi) {
  int flat = blockIdx.x * 256 + threadIdx.x;   // 16*16*64 = 16384
  int l = flat & 63, ntkc = flat >> 6;
  int nt = ntkc >> 4, kc = ntkc & 15;
  int n = nt * 16 + (l & 15);
  int kbase = kc * 32 + (l >> 4) * 8;
  unsigned short e[8];
#pragma unroll
  for (int j = 0; j < 8; ++j) e[j] = f2bf(W_i2h[(size_t)n * DD + kbase + j]);
  uint4 o = {pk(e[0], e[1]), pk(e[2], e[3]), pk(e[4], e[5]), pk(e[6], e[7])};
  ((uint4*)Wi)[flat] = o;
}

// W_gen [38][256] -> bf16 MFMA-B swizzled [nt(3)][kc(8)][lane][8], cols padded to 48
__global__ __launch_bounds__(256) void prep_wgen_kernel(const float* __restrict__ W_gen,
                                                        unsigned short* __restrict__ Wgp) {
  int flat = blockIdx.x * 256 + threadIdx.x;   // 3*8*64 = 1536
  if (flat >= 1536) return;
  int l = flat & 63, ntkc = flat >> 6;
  int nt = ntkc >> 3, kc = ntkc & 7;
  int n = nt * 16 + (l & 15);
  int kbase = kc * 32 + (l >> 4) * 8;
  unsigned short e[8];
#pragma unroll
  for (int j = 0; j < 8; ++j)
    e[j] = (n < NCLS) ? f2bf(W_gen[(size_t)n * HH + kbase + j]) : (unsigned short)0;
  uint4 o = {pk(e[0], e[1]), pk(e[2], e[3]), pk(e[4], e[5]), pk(e[6], e[7])};
  ((uint4*)Wgp)[flat] = o;
}

// W_h2h [256][256] -> bf16 MFMA-B swizzled [nt(16)][kc(8)][lane][8]; plus bc = b_ih+b_hh
__global__ __launch_bounds__(256) void prep_whb_bc_kernel(const float* __restrict__ W_h2h,
                                                          const float* __restrict__ b_ih,
                                                          const float* __restrict__ b_hh,
                                                          unsigned short* __restrict__ Whb,
                                                          float* __restrict__ bc) {
  int flat = blockIdx.x * 256 + threadIdx.x;   // 16*8*64 = 8192
  if (flat >= 8192) return;
  int l = flat & 63, ntkc = flat >> 6;
  int nt = ntkc >> 3, kc = ntkc & 7;
  int n = nt * 16 + (l & 15);
  int kbase = kc * 32 + (l >> 4) * 8;
  unsigned short e[8];
#pragma unroll
  for (int j = 0; j < 8; ++j) e[j] = f2bf(W_h2h[(size_t)n * HH + kbase + j]);
  uint4 o = {pk(e[0], e[1]), pk(e[2], e[3]), pk(e[4], e[5]), pk(e[6], e[7])};
  ((uint4*)Whb)[flat] = o;
  if (flat < 1024) bc[flat] = b_ih[flat] + b_hh[flat];
}

// ---------------------------------------------------------------------------
// H_proj = batch_H(bf16) @ W_i2h^T -> bf16 [65536][256]; 512 blocks * 128 rows
__global__ __launch_bounds__(256) void hproj_mfma_kernel(const unsigned short* __restrict__ Abf,
                                                         const unsigned short* __restrict__ Wi,
                                                         unsigned short* __restrict__ Hbf) {
  const int tid = threadIdx.x;
  const int w = tid >> 6, l = tid & 63;
  const int li = l & 15, qd = l >> 4;
  const int m0 = blockIdx.x * 128 + w * 32;
  f32x4 acc[2][16];
#pragma unroll
  for (int a = 0; a < 2; ++a)
#pragma unroll
    for (int b = 0; b < 16; ++b) acc[a][b] = (f32x4){0.f, 0.f, 0.f, 0.f};
  const bf16x8* Wi8 = (const bf16x8*)Wi;
  for (int kc = 0; kc < 16; ++kc) {
    bf16x8 a0 = *(const bf16x8*)(Abf + (size_t)(m0 + li) * DD + kc * 32 + qd * 8);
    bf16x8 a1 = *(const bf16x8*)(Abf + (size_t)(m0 + 16 + li) * DD + kc * 32 + qd * 8);
#pragma unroll
    for (int nt = 0; nt < 16; ++nt) {
      bf16x8 b = Wi8[(nt * 16 + kc) * 64 + l];
      acc[0][nt] = __builtin_amdgcn_mfma_f32_16x16x32_bf16(a0, b, acc[0][nt], 0, 0, 0);
      acc[1][nt] = __builtin_amdgcn_mfma_f32_16x16x32_bf16(a1, b, acc[1][nt], 0, 0, 0);
    }
  }
#pragma unroll
  for (int mi = 0; mi < 2; ++mi)
#pragma unroll
    for (int nt = 0; nt < 16; ++nt)
#pragma unroll
      for (int r = 0; r < 4; ++r) {
        int row = m0 + mi * 16 + qd * 4 + r;
        Hbf[(size_t)row * HH + nt * 16 + li] = f2bf(acc[mi][nt][r]);
      }
}

// ---------------------------------------------------------------------------
// Persistent fused decode: 256 blocks x 512 threads; block owns rows 8b..8b+7.
// Phase E: Wg kc-slices (64 KB) DMA'd global->LDS double-buffered (deep pipeline).
// Phase B: H_proj read from global with sc1 (L3-resident, L2-bypass).
// Phase D: batch_H streamed with sc1. L2 per XCD holds only Wg (1.7 MB).
//
// LDS layout (dynamic, 162816 B):
#define LDS_WS    0        // 131072: Wg kc-slice double buffer (2 x 64 KiB)
#define LDS_XA    131072   //  18432: gates-A chunks [kc=18][lane=64][8bf16], XOR-swz
#define LDS_HL    149504   //   4096: h bf16 [row=8][256], byte ^= (row&7)<<4
#define LDS_HPF   153600   //   8192: hp f32 [8][256]
#define LDS_SE    161792   //   1024: e/alpha f32 [8][32]
#define LDS_TOTAL 162816

__global__ __launch_bounds__(512)
void decode_kernel(
    const unsigned short* __restrict__ bHbf, const unsigned short* __restrict__ Hbf,
    const unsigned short* __restrict__ Wg, const unsigned short* __restrict__ Whb,
    const unsigned short* __restrict__ Wgp, const float* __restrict__ bc,
    const float* __restrict__ b_h2h, const float* __restrict__ W_score,
    const float* __restrict__ b_gen, const int* __restrict__ text,
    float* __restrict__ out) {
  extern __shared__ char lds[];
  char* WS = lds + LDS_WS;
  char* XA = lds + LDS_XA;
  char* HL = lds + LDS_HL;
  float* HPF = (float*)(lds + LDS_HPF);
  float* SE = (float*)(lds + LDS_SE);

  const int tid = threadIdx.x;
  const int w = tid >> 6, ln = tid & 63;
  const int li = ln & 15, qd = ln >> 4;
  const int b0 = blockIdx.x * 8;
  const int hrow = ln & 7;   // MFMA A-frag h-row (rows 8..15 duplicate 0..7, discarded)

  // ---- init: zero XA + HL (contiguous, 22528 B)
  for (int off = tid; off < (18432 + 4096) / 4; off += 512) ((float*)XA)[off] = 0.f;

  f32x4 cst[2] = {{0.f, 0.f, 0.f, 0.f}, {0.f, 0.f, 0.f, 0.f}};  // c state
  __syncthreads();

  // per-wave batch_H row base for phase D streaming
  const u32x4* bhsrc = (const u32x4*)(bHbf + (size_t)(b0 + w) * TT * DD) + ln;

  for (int s = 0; s < NSTEP; ++s) {
    // ---- prefetch Wg kc=0 slice into WS buf0 (lands long before phase E)
    {
      const unsigned short* sb = Wg;
      char* db = WS;
#pragma unroll
      for (int q = 0; q < 8; ++q)
        stage16(sb + (q * 512 + tid) * 8, db + (q * 512 + tid) * 16);
    }

    // ---- A: hp = h @ W_h2h^T + b_h2h  (16-row M-tile, 8 valid; wave w -> nt 2w..2w+1)
    {
      f32x4 hacc[2] = {{0.f, 0.f, 0.f, 0.f}, {0.f, 0.f, 0.f, 0.f}};
      const bf16x8* WB = (const bf16x8*)Whb;
#pragma unroll
      for (int kc = 0; kc < 8; ++kc) {
        bf16x8 a = *(const bf16x8*)(HL + hrow * 512 + ((kc * 64 + qd * 16) ^ (hrow << 4)));
#pragma unroll
        for (int n = 0; n < 2; ++n) {
          bf16x8 b = WB[((w * 2 + n) * 8 + kc) * 64 + ln];
          hacc[n] = __builtin_amdgcn_mfma_f32_16x16x32_bf16(a, b, hacc[n], 0, 0, 0);
        }
      }
      if (qd < 2) {
#pragma unroll
        for (int n = 0; n < 2; ++n) {
          int col = (w * 2 + n) * 16 + li;
          float bb = b_h2h[col];
#pragma unroll
          for (int r = 0; r < 4; ++r) HPF[(qd * 4 + r) * 256 + col] = hacc[n][r] + bb;
        }
      }
    }
    __syncthreads();

    // ---- B: e[i][t] = sum_j tanh(Hproj + hp) * ws ; Hproj from global (sc1, L3)
    {
      const int sub = ln >> 3, li8 = ln & 7;
#pragma unroll 1
      for (int p = 0; p < 4; ++p) {
        int pi = p * 64 + w * 8 + sub;       // it = i*32 + t
        int i = pi >> 5;
        const unsigned short* hb = Hbf + ((size_t)b0 * TT + pi) * HH + li8 * 8;
        u32x4 h0, h1, h2, h3;
        asm volatile(
            "global_load_dwordx4 %0, %4, off sc1 nt\n\t"
            "global_load_dwordx4 %1, %4, off offset:128 sc1 nt\n\t"
            "global_load_dwordx4 %2, %4, off offset:256 sc1 nt\n\t"
            "global_load_dwordx4 %3, %4, off offset:384 sc1 nt\n\t"
            "s_waitcnt vmcnt(0)"
            : "=&v"(h0), "=&v"(h1), "=&v"(h2), "=&v"(h3)
            : "v"(hb));
        u32x4 hvs[4] = {h0, h1, h2, h3};
        float v = 0.f;
#pragma unroll
        for (int c = 0; c < 4; ++c) {
          int j = c * 64 + li8 * 8;
          u32x4 hv = hvs[c];
          float4 hp0 = *(const float4*)(HPF + i * 256 + j);
          float4 hp1 = *(const float4*)(HPF + i * 256 + j + 4);
          float4 ws0 = *(const float4*)(W_score + j);
          float4 ws1 = *(const float4*)(W_score + j + 4);
          v += fast_tanh(bf2f((unsigned short)(hv.x & 0xFFFF)) + hp0.x) * ws0.x;
          v += fast_tanh(bf2f((unsigned short)(hv.x >> 16))    + hp0.y) * ws0.y;
          v += fast_tanh(bf2f((unsigned short)(hv.y & 0xFFFF)) + hp0.z) * ws0.z;
          v += fast_tanh(bf2f((unsigned short)(hv.y >> 16))    + hp0.w) * ws0.w;
          v += fast_tanh(bf2f((unsigned short)(hv.z & 0xFFFF)) + hp1.x) * ws1.x;
          v += fast_tanh(bf2f((unsigned short)(hv.z >> 16))    + hp1.y) * ws1.y;
          v += fast_tanh(bf2f((unsigned short)(hv.w & 0xFFFF)) + hp1.z) * ws1.z;
          v += fast_tanh(bf2f((unsigned short)(hv.w >> 16))    + hp1.w) * ws1.w;
        }
        v += __shfl_xor(v, 1, 64);
        v += __shfl_xor(v, 2, 64);
        v += __shfl_xor(v, 4, 64);
        if (li8 == 0) SE[pi] = v;   // SE[i*32+t]
      }
    }
    __syncthreads();

    // ---- C: softmax over t (32-lane groups)
    if (tid < 256) {
      float e = SE[tid];
      float mx = e;
#pragma unroll
      for (int m = 16; m >= 1; m >>= 1) mx = fmaxf(mx, __shfl_xor(mx, m, 32));
      float pexp = __expf(e - mx);
      float ssum = pexp;
#pragma unroll
      for (int m = 16; m >= 1; m >>= 1) ssum += __shfl_xor(ssum, m, 32);
      SE[tid] = pexp / ssum;
    }
    __syncthreads();

    // ---- D: context streamed from global with sc1 (L2-bypass) loads -> XA (swz)
    {
      float acc[8] = {0.f, 0.f, 0.f, 0.f, 0.f, 0.f, 0.f, 0.f};
      const float* al = SE + w * 32;
#pragma unroll 1
      for (int tb = 0; tb < 8; ++tb) {
        const u32x4* p0 = &bhsrc[(tb * 4 + 0) * 64];
        const u32x4* p1 = &bhsrc[(tb * 4 + 1) * 64];
        const u32x4* p2 = &bhsrc[(tb * 4 + 2) * 64];
        const u32x4* p3 = &bhsrc[(tb * 4 + 3) * 64];
        u32x4 h0, h1, h2, h3;
        asm volatile(
            "global_load_dwordx4 %0, %4, off sc1 nt\n\t"
            "global_load_dwordx4 %1, %5, off sc1 nt\n\t"
            "global_load_dwordx4 %2, %6, off sc1 nt\n\t"
            "global_load_dwordx4 %3, %7, off sc1 nt\n\t"
            "s_waitcnt vmcnt(0)"
            : "=&v"(h0), "=&v"(h1), "=&v"(h2), "=&v"(h3)
            : "v"(p0), "v"(p1), "v"(p2), "v"(p3));
        u32x4 hvb[4] = {h0, h1, h2, h3};
#pragma unroll
        for (int u = 0; u < 4; ++u) {
          float a = al[tb * 4 + u];
          u32x4 hv = hvb[u];
          acc[0] += a * bf2f((unsigned short)(hv.x & 0xFFFF));
          acc[1] += a * bf2f((unsigned short)(hv.x >> 16));
          acc[2] += a * bf2f((unsigned short)(hv.y & 0xFFFF));
          acc[3] += a * bf2f((unsigned short)(hv.y >> 16));
          acc[4] += a * bf2f((unsigned short)(hv.z & 0xFFFF));
          acc[5] += a * bf2f((unsigned short)(hv.z >> 16));
          acc[6] += a * bf2f((unsigned short)(hv.w & 0xFFFF));
          acc[7] += a * bf2f((unsigned short)(hv.w >> 16));
        }
      }
      uint4 o = {pk(f2bf(acc[0]), f2bf(acc[1])), pk(f2bf(acc[2]), f2bf(acc[3])),
                 pk(f2bf(acc[4]), f2bf(acc[5])), pk(f2bf(acc[6]), f2bf(acc[7]))};
      int kc = ln >> 2, q = ln & 3;
      int lane_t = q * 16 + w;
      *(uint4*)(XA + kc * 1024 + ((lane_t * 16) ^ ((kc & 7) << 4))) = o;
    }
    if (tid < 64) {
      int row = tid >> 3, sl = tid & 7;
      int kc = 16 + (sl >> 2), q = sl & 3;
      int cc0 = (sl >> 2) * 32 + q * 8;     // onehot class base for this slot
      int ch = text[(b0 + row) * NSTEP + s];
      unsigned short e8[8];
#pragma unroll
      for (int j = 0; j < 8; ++j)
        e8[j] = (cc0 + j == ch) ? (unsigned short)0x3F80 : (unsigned short)0;
      uint4 o = {pk(e8[0], e8[1]), pk(e8[2], e8[3]), pk(e8[4], e8[5]), pk(e8[6], e8[7])};
      int lane_t = q * 16 + row;
      *(uint4*)(XA + kc * 1024 + ((lane_t * 16) ^ ((kc & 7) << 4))) = o;
    }
    __syncthreads();   // also drains the kc=0 Wg stage into WS buf0

    // ---- E: gates MFMA; Wg kc-slices double-buffered via global_load_lds
    f32x4 acc[8];
#pragma unroll
    for (int n = 0; n < 8; ++n) acc[n] = (f32x4){0.f, 0.f, 0.f, 0.f};
    {
#pragma unroll 1
      for (int kc = 0; kc < NKC; ++kc) {
        if (kc + 1 < NKC) {                  // stage next slice into other buffer
          const unsigned short* sb = Wg + (size_t)(kc + 1) * 32768;
          char* db = WS + (((kc + 1) & 1) << 16);
#pragma unroll
          for (int q = 0; q < 8; ++q)
            stage16(sb + (q * 512 + tid) * 8, db + (q * 512 + tid) * 16);
        }
        bf16x8 a;
        if (kc < 18) {
          a = *(const bf16x8*)(XA + kc * 1024 + ((ln * 16) ^ ((kc & 7) << 4)));
        } else {
          int kk = (kc - 18) * 64 + qd * 16;
          a = *(const bf16x8*)(HL + hrow * 512 + (kk ^ (hrow << 4)));
        }
        const char* wb = WS + ((kc & 1) << 16) + (w * 512 + ln) * 16;
#pragma unroll
        for (int n = 0; n < 8; ++n) {
          bf16x8 b = *(const bf16x8*)(wb + n * 1024);
          acc[n] = __builtin_amdgcn_mfma_f32_16x16x32_bf16(a, b, acc[n], 0, 0, 0);
        }
        __syncthreads();   // next slice landed; current slice free for reuse
      }
    }
    unsigned short hreg[2][4];
    if (qd < 2) {
#pragma unroll
      for (int k = 0; k < 2; ++k) {
        int jg = (2 * w + k) * 16 + li;
        float bci = bc[jg], bcf = bc[256 + jg], bcg = bc[512 + jg], bco = bc[768 + jg];
#pragma unroll
        for (int r = 0; r < 4; ++r) {
          float iv = fast_sigmoid(acc[k * 4 + 0][r] + bci);
          float fv = fast_sigmoid(acc[k * 4 + 1][r] + bcf);
          float gv = fast_tanh   (acc[k * 4 + 2][r] + bcg);
          float ov = fast_sigmoid(acc[k * 4 + 3][r] + bco);
          float cn = fv * cst[k][r] + iv * gv;
          cst[k][r] = cn;
          hreg[k][r] = f2bf(ov * fast_tanh(cn));
        }
      }
    }
    __syncthreads();   // all MFMA reads of h(s-1) complete before overwrite

    // ---- F: write h(s) to HL (swizzled)
    if (qd < 2) {
#pragma unroll
      for (int k = 0; k < 2; ++k) {
        int jg = (2 * w + k) * 16 + li;
#pragma unroll
        for (int r = 0; r < 4; ++r) {
          int row = qd * 4 + r;
          *(unsigned short*)(HL + row * 512 + ((jg * 2) ^ (row << 4))) = hreg[k][r];
        }
      }
    }
    __syncthreads();

    // ---- G: probs(s) = h(s) @ W_gen^T + b_gen (waves 0..2; no barrier needed after)
    if (w < 3) {
      f32x4 pa = {0.f, 0.f, 0.f, 0.f};
      const bf16x8* W8 = (const bf16x8*)Wgp;
#pragma unroll
      for (int kc = 0; kc < 8; ++kc) {
        bf16x8 a = *(const bf16x8*)(HL + hrow * 512 + ((kc * 64 + qd * 16) ^ (hrow << 4)));
        bf16x8 b = W8[(w * 8 + kc) * 64 + ln];
        pa = __builtin_amdgcn_mfma_f32_16x16x32_bf16(a, b, pa, 0, 0, 0);
      }
      int col = w * 16 + li;
      if (qd < 2 && col < NCLS) {
        float bg = b_gen[col];
#pragma unroll
        for (int r = 0; r < 4; ++r) {
          int row = qd * 4 + r;
          out[((size_t)(b0 + row) * NSTEP + s) * NCLS + col] = pa[r] + bg;
        }
      }
    }
  }
}

// ---------------------------------------------------------------------------
extern "C" void kernel_launch(void* const* d_in, const int* in_sizes, int n_in,
                              void* d_out, int out_size, void* d_ws, size_t ws_size,
                              hipStream_t stream) {
  const float* batch_H = (const float*)d_in[0];
  const int*   text    = (const int*)d_in[1];
  const float* W_i2h   = (const float*)d_in[2];
  const float* W_h2h   = (const float*)d_in[3];
  const float* b_h2h   = (const float*)d_in[4];
  const float* W_score = (const float*)d_in[5];
  const float* W_ih    = (const float*)d_in[6];
  const float* b_ih    = (const float*)d_in[7];
  const float* W_hh    = (const float*)d_in[8];
  const float* b_hh    = (const float*)d_in[9];
  const float* W_gen   = (const float*)d_in[10];
  const float* b_gen   = (const float*)d_in[11];
  float* out = (float*)d_out;

  // workspace layout (bytes)
  char* p = (char*)d_ws;
  unsigned short* bHbf = (unsigned short*)p;  p += (size_t)2048 * 32 * 512 * 2;  // 64 MiB
  unsigned short* Hbf  = (unsigned short*)p;  p += (size_t)65536 * 256 * 2;      // 32 MiB
  unsigned short* Wg   = (unsigned short*)p;  p += (size_t)64 * NKC * 64 * 8 * 2;
  unsigned short* Wi   = (unsigned short*)p;  p += (size_t)256 * 512 * 2;
  unsigned short* Wgp  = (unsigned short*)p;  p += (size_t)3 * 8 * 64 * 8 * 2;
  unsigned short* Whb  = (unsigned short*)p;  p += (size_t)16 * 8 * 64 * 8 * 2;
  float* bc            = (float*)p;           p += (size_t)1024 * 4;

  static int attr_done = 0;
  if (!attr_done) {
    hipFuncSetAttribute((const void*)decode_kernel,
                        hipFuncAttributeMaxDynamicSharedMemorySize, LDS_TOTAL);
    attr_done = 1;
  }

  cvt_bh_kernel<<<16384, 256, 0, stream>>>(batch_H, bHbf);
  prep_wg_kernel<<<416, 256, 0, stream>>>(W_ih, W_hh, Wg);
  prep_wi_kernel<<<64, 256, 0, stream>>>(W_i2h, Wi);
  prep_wgen_kernel<<<6, 256, 0, stream>>>(W_gen, Wgp);
  prep_whb_bc_kernel<<<32, 256, 0, stream>>>(W_h2h, b_ih, b_hh, Whb, bc);
  hproj_mfma_kernel<<<512, 256, 0, stream>>>(bHbf, Wi, Hbf);
  decode_kernel<<<256, 512, LDS_TOTAL, stream>>>(bHbf, Hbf, Wg, Whb, Wgp, bc,
                                                 b_h2h, W_score, b_gen, text, out);
}

// Round 9
// 1326.923 us; speedup vs baseline: 4.0123x; 1.0995x over previous
//
#include <hip/hip_runtime.h>
#include <cstddef>

// Problem constants
#define TT    32       // T_ENC
#define DD    512      // D_IN
#define HH    256      // hidden
#define NCLS  38       // classes
#define NSTEP 26       // MAXLEN+1
#define NKC   26       // K chunks of 32 for gates GEMM (16 ctx + 2 onehot + 8 h)

typedef float f32x4 __attribute__((ext_vector_type(4)));
typedef short bf16x8 __attribute__((ext_vector_type(8)));
typedef unsigned int u32x4 __attribute__((ext_vector_type(4)));

__device__ __forceinline__ float fast_tanh(float z) {
  float e = __expf(2.f * z);
  return 1.f - 2.f / (e + 1.f);
}
__device__ __forceinline__ float fast_sigmoid(float z) {
  return 1.f / (1.f + __expf(-z));
}
__device__ __forceinline__ float bf2f(unsigned short s) {
  union { unsigned int u; float f; } v; v.u = ((unsigned int)s) << 16; return v.f;
}
__device__ __forceinline__ unsigned short f2bf(float f) {  // RNE
  union { float ff; unsigned int u; } v; v.ff = f;
  unsigned int r = v.u + 0x7FFFu + ((v.u >> 16) & 1u);
  return (unsigned short)(r >> 16);
}
__device__ __forceinline__ unsigned int pk(unsigned short a, unsigned short b) {
  return (unsigned int)a | ((unsigned int)b << 16);
}

// async global->LDS 16B copy (DMA; dest = wave-uniform base + lane*16)
__device__ __forceinline__ void stage16(const void* g, void* l) {
  __builtin_amdgcn_global_load_lds(
      (const __attribute__((address_space(1))) unsigned int*)g,
      (__attribute__((address_space(3))) unsigned int*)l, 16, 0, 0);
}

// ---------------------------------------------------------------------------
// batch_H fp32 -> bf16 row-major (33,554,432 elems; 8 per thread; grid 16384)
__global__ __launch_bounds__(256) void cvt_bh_kernel(const float* __restrict__ src,
                                                     unsigned short* __restrict__ dst) {
  int t = blockIdx.x * 256 + threadIdx.x;
  const float4* s4 = (const float4*)src + (size_t)t * 2;
  float4 a = s4[0], b = s4[1];
  uint4 o;
  o.x = pk(f2bf(a.x), f2bf(a.y));
  o.y = pk(f2bf(a.z), f2bf(a.w));
  o.z = pk(f2bf(b.x), f2bf(b.y));
  o.w = pk(f2bf(b.z), f2bf(b.w));
  ((uint4*)dst)[t] = o;
}

// gates weights bf16, MFMA-B swizzled, nt-major: [nt(64)][kc(26)][lane][8].
// col = nt*16 + li ; gate = nt&3 ; jg = (nt>>2)*16 + li
// nt-major so each wave's (nt=8w..8w+7, kc) slice is 8 contiguous 1 KB blocks.
__global__ __launch_bounds__(256) void prep_wg_kernel(const float* __restrict__ W_ih,
                                                      const float* __restrict__ W_hh,
                                                      unsigned short* __restrict__ Wg) {
  int flat = blockIdx.x * 256 + threadIdx.x;   // 64*NKC*64 = 106496
  if (flat >= 64 * NKC * 64) return;
  int l = flat & 63, ntkc = flat >> 6;
  int nt = ntkc / NKC, kc = ntkc - nt * NKC;
  int gate = nt & 3;
  int jg = (nt >> 2) * 16 + (l & 15);
  int orig = gate * 256 + jg;
  int kbase = kc * 32 + (l >> 4) * 8;
  unsigned short e[8];
#pragma unroll
  for (int j = 0; j < 8; ++j) {
    int k = kbase + j;
    float v;
    if (k < DD + NCLS)      v = W_ih[orig * (DD + NCLS) + k];
    else if (k < 576)       v = 0.f;                       // pad 550..575
    else                    v = W_hh[orig * HH + (k - 576)];
    e[j] = f2bf(v);
  }
  uint4 o = {pk(e[0], e[1]), pk(e[2], e[3]), pk(e[4], e[5]), pk(e[6], e[7])};
  ((uint4*)Wg)[flat] = o;
}

// W_i2h [256][512] -> bf16 MFMA-B swizzled [nt(16)][kc(16)][lane][8]
__global__ __launch_bounds__(256) void prep_wi_kernel(const float* __restrict__ W_i2h,
                                                      unsigned short* __restrict__ Wi) {
  int flat = blockIdx.x * 256 + threadIdx.x;   // 16*16*64 = 16384
  int l = flat & 63, ntkc = flat >> 6;
  int nt = ntkc >> 4, kc = ntkc & 15;
  int n = nt * 16 + (l & 15);
  int kbase = kc * 32 + (l >> 4) * 8;
  unsigned short e[8];
#pragma unroll
  for (int j = 0; j < 8; ++j) e[j] = f2bf(W_i2h[(size_t)n * DD + kbase + j]);
  uint4 o = {pk(e[0], e[1]), pk(e[2], e[3]), pk(e[4], e[5]), pk(e[6], e[7])};
  ((uint4*)Wi)[flat] = o;
}

// W_gen [38][256] -> bf16 MFMA-B swizzled [nt(3)][kc(8)][lane][8], cols padded to 48
__global__ __launch_bounds__(256) void prep_wgen_kernel(const float* __restrict__ W_gen,
                                                        unsigned short* __restrict__ Wgp) {
  int flat = blockIdx.x * 256 + threadIdx.x;   // 3*8*64 = 1536
  if (flat >= 1536) return;
  int l = flat & 63, ntkc = flat >> 6;
  int nt = ntkc >> 3, kc = ntkc & 7;
  int n = nt * 16 + (l & 15);
  int kbase = kc * 32 + (l >> 4) * 8;
  unsigned short e[8];
#pragma unroll
  for (int j = 0; j < 8; ++j)
    e[j] = (n < NCLS) ? f2bf(W_gen[(size_t)n * HH + kbase + j]) : (unsigned short)0;
  uint4 o = {pk(e[0], e[1]), pk(e[2], e[3]), pk(e[4], e[5]), pk(e[6], e[7])};
  ((uint4*)Wgp)[flat] = o;
}

// W_h2h [256][256] -> bf16 MFMA-B swizzled [nt(16)][kc(8)][lane][8]; plus bc = b_ih+b_hh
__global__ __launch_bounds__(256) void prep_whb_bc_kernel(const float* __restrict__ W_h2h,
                                                          const float* __restrict__ b_ih,
                                                          const float* __restrict__ b_hh,
                                                          unsigned short* __restrict__ Whb,
                                                          float* __restrict__ bc) {
  int flat = blockIdx.x * 256 + threadIdx.x;   // 16*8*64 = 8192
  if (flat >= 8192) return;
  int l = flat & 63, ntkc = flat >> 6;
  int nt = ntkc >> 3, kc = ntkc & 7;
  int n = nt * 16 + (l & 15);
  int kbase = kc * 32 + (l >> 4) * 8;
  unsigned short e[8];
#pragma unroll
  for (int j = 0; j < 8; ++j) e[j] = f2bf(W_h2h[(size_t)n * HH + kbase + j]);
  uint4 o = {pk(e[0], e[1]), pk(e[2], e[3]), pk(e[4], e[5]), pk(e[6], e[7])};
  ((uint4*)Whb)[flat] = o;
  if (flat < 1024) bc[flat] = b_ih[flat] + b_hh[flat];
}

// ---------------------------------------------------------------------------
// H_proj = batch_H(bf16) @ W_i2h^T -> bf16 [65536][256]; 512 blocks * 128 rows
__global__ __launch_bounds__(256) void hproj_mfma_kernel(const unsigned short* __restrict__ Abf,
                                                         const unsigned short* __restrict__ Wi,
                                                         unsigned short* __restrict__ Hbf) {
  const int tid = threadIdx.x;
  const int w = tid >> 6, l = tid & 63;
  const int li = l & 15, qd = l >> 4;
  const int m0 = blockIdx.x * 128 + w * 32;
  f32x4 acc[2][16];
#pragma unroll
  for (int a = 0; a < 2; ++a)
#pragma unroll
    for (int b = 0; b < 16; ++b) acc[a][b] = (f32x4){0.f, 0.f, 0.f, 0.f};
  const bf16x8* Wi8 = (const bf16x8*)Wi;
  for (int kc = 0; kc < 16; ++kc) {
    bf16x8 a0 = *(const bf16x8*)(Abf + (size_t)(m0 + li) * DD + kc * 32 + qd * 8);
    bf16x8 a1 = *(const bf16x8*)(Abf + (size_t)(m0 + 16 + li) * DD + kc * 32 + qd * 8);
#pragma unroll
    for (int nt = 0; nt < 16; ++nt) {
      bf16x8 b = Wi8[(nt * 16 + kc) * 64 + l];
      acc[0][nt] = __builtin_amdgcn_mfma_f32_16x16x32_bf16(a0, b, acc[0][nt], 0, 0, 0);
      acc[1][nt] = __builtin_amdgcn_mfma_f32_16x16x32_bf16(a1, b, acc[1][nt], 0, 0, 0);
    }
  }
#pragma unroll
  for (int mi = 0; mi < 2; ++mi)
#pragma unroll
    for (int nt = 0; nt < 16; ++nt)
#pragma unroll
      for (int r = 0; r < 4; ++r) {
        int row = m0 + mi * 16 + qd * 4 + r;
        Hbf[(size_t)row * HH + nt * 16 + li] = f2bf(acc[mi][nt][r]);
      }
}

// ---------------------------------------------------------------------------
// Persistent fused decode: 256 blocks x 512 threads; block owns rows 8b..8b+7.
// Phase E: Wg staged per-wave (wave w reads only nt 8w..8w+7) into a private
// 16 KB LDS region, double-buffered with COUNTED vmcnt waits — no barriers in
// the kc loop. kc0/kc1 of the next step prefetched at end of E (drained by D).
// Phase B: H_proj via sc1 (L3). Phase D: batch_H via sc1. L2 holds only Wg.
//
// LDS layout (dynamic, 162816 B):
#define LDS_WS    0        // 131072: Wg stage, 8 waves x (2 bufs x 8 KiB)
#define LDS_XA    131072   //  18432: gates-A chunks [kc=18][lane=64][8bf16], XOR-swz
#define LDS_HL    149504   //   4096: h bf16 [row=8][256], byte ^= (row&7)<<4
#define LDS_HPF   153600   //   8192: hp f32 [8][256]
#define LDS_SE    161792   //   1024: e/alpha f32 [8][32]
#define LDS_TOTAL 162816

__global__ __launch_bounds__(512)
void decode_kernel(
    const unsigned short* __restrict__ bHbf, const unsigned short* __restrict__ Hbf,
    const unsigned short* __restrict__ Wg, const unsigned short* __restrict__ Whb,
    const unsigned short* __restrict__ Wgp, const float* __restrict__ bc,
    const float* __restrict__ b_h2h, const float* __restrict__ W_score,
    const float* __restrict__ b_gen, const int* __restrict__ text,
    float* __restrict__ out) {
  extern __shared__ char lds[];
  char* WS = lds + LDS_WS;
  char* XA = lds + LDS_XA;
  char* HL = lds + LDS_HL;
  float* HPF = (float*)(lds + LDS_HPF);
  float* SE = (float*)(lds + LDS_SE);

  const int tid = threadIdx.x;
  const int w = tid >> 6, ln = tid & 63;
  const int li = ln & 15, qd = ln >> 4;
  const int b0 = blockIdx.x * 8;
  const int hrow = ln & 7;   // MFMA A-frag h-row (rows 8..15 duplicate 0..7, discarded)

  char* wsw = WS + w * 16384;   // wave-private stage region (2 x 8 KiB)

  // per-wave stage of one kc-slice (8 x 1 KiB) into buffer `buf`
  auto STAGE = [&](int kc, int buf) {
#pragma unroll
    for (int n = 0; n < 8; ++n)
      stage16(Wg + ((size_t)((w * 8 + n) * NKC + kc)) * 512 + ln * 8,
              wsw + buf * 8192 + n * 1024 + ln * 16);
  };
  auto RDB = [&](int buf, bf16x8* bfr) {
#pragma unroll
    for (int n = 0; n < 8; ++n)
      bfr[n] = *(const bf16x8*)(wsw + buf * 8192 + n * 1024 + ln * 16);
  };
  auto LDA = [&](int kc) -> bf16x8 {
    if (kc < 18)
      return *(const bf16x8*)(XA + kc * 1024 + ((ln * 16) ^ ((kc & 7) << 4)));
    int kk = (kc - 18) * 64 + qd * 16;
    return *(const bf16x8*)(HL + hrow * 512 + (kk ^ (hrow << 4)));
  };

  // ---- init: zero XA + HL (contiguous, 22528 B)
  for (int off = tid; off < (18432 + 4096) / 4; off += 512) ((float*)XA)[off] = 0.f;

  // initial Wg prefetch: kc0 -> buf0, kc1 -> buf1 (drains under phases A..D)
  STAGE(0, 0);
  STAGE(1, 1);

  f32x4 cst[2] = {{0.f, 0.f, 0.f, 0.f}, {0.f, 0.f, 0.f, 0.f}};  // c state
  __syncthreads();

  // per-wave batch_H row base for phase D streaming
  const u32x4* bhsrc = (const u32x4*)(bHbf + (size_t)(b0 + w) * TT * DD) + ln;

  for (int s = 0; s < NSTEP; ++s) {
    // ---- A: hp = h @ W_h2h^T + b_h2h  (16-row M-tile, 8 valid; wave w -> nt 2w..2w+1)
    {
      f32x4 hacc[2] = {{0.f, 0.f, 0.f, 0.f}, {0.f, 0.f, 0.f, 0.f}};
      const bf16x8* WB = (const bf16x8*)Whb;
#pragma unroll
      for (int kc = 0; kc < 8; ++kc) {
        bf16x8 a = *(const bf16x8*)(HL + hrow * 512 + ((kc * 64 + qd * 16) ^ (hrow << 4)));
#pragma unroll
        for (int n = 0; n < 2; ++n) {
          bf16x8 b = WB[((w * 2 + n) * 8 + kc) * 64 + ln];
          hacc[n] = __builtin_amdgcn_mfma_f32_16x16x32_bf16(a, b, hacc[n], 0, 0, 0);
        }
      }
      if (qd < 2) {
#pragma unroll
        for (int n = 0; n < 2; ++n) {
          int col = (w * 2 + n) * 16 + li;
          float bb = b_h2h[col];
#pragma unroll
          for (int r = 0; r < 4; ++r) HPF[(qd * 4 + r) * 256 + col] = hacc[n][r] + bb;
        }
      }
    }
    __syncthreads();

    // ---- B: e[i][t] = sum_j tanh(Hproj + hp) * ws ; Hproj from global (sc1, L3)
    {
      const int sub = ln >> 3, li8 = ln & 7;
#pragma unroll 1
      for (int p = 0; p < 4; ++p) {
        int pi = p * 64 + w * 8 + sub;       // it = i*32 + t
        int i = pi >> 5;
        const unsigned short* hb = Hbf + ((size_t)b0 * TT + pi) * HH + li8 * 8;
        u32x4 h0, h1, h2, h3;
        asm volatile(
            "global_load_dwordx4 %0, %4, off sc1 nt\n\t"
            "global_load_dwordx4 %1, %4, off offset:128 sc1 nt\n\t"
            "global_load_dwordx4 %2, %4, off offset:256 sc1 nt\n\t"
            "global_load_dwordx4 %3, %4, off offset:384 sc1 nt\n\t"
            "s_waitcnt vmcnt(0)"
            : "=&v"(h0), "=&v"(h1), "=&v"(h2), "=&v"(h3)
            : "v"(hb));
        u32x4 hvs[4] = {h0, h1, h2, h3};
        float v = 0.f;
#pragma unroll
        for (int c = 0; c < 4; ++c) {
          int j = c * 64 + li8 * 8;
          u32x4 hv = hvs[c];
          float4 hp0 = *(const float4*)(HPF + i * 256 + j);
          float4 hp1 = *(const float4*)(HPF + i * 256 + j + 4);
          float4 ws0 = *(const float4*)(W_score + j);
          float4 ws1 = *(const float4*)(W_score + j + 4);
          v += fast_tanh(bf2f((unsigned short)(hv.x & 0xFFFF)) + hp0.x) * ws0.x;
          v += fast_tanh(bf2f((unsigned short)(hv.x >> 16))    + hp0.y) * ws0.y;
          v += fast_tanh(bf2f((unsigned short)(hv.y & 0xFFFF)) + hp0.z) * ws0.z;
          v += fast_tanh(bf2f((unsigned short)(hv.y >> 16))    + hp0.w) * ws0.w;
          v += fast_tanh(bf2f((unsigned short)(hv.z & 0xFFFF)) + hp1.x) * ws1.x;
          v += fast_tanh(bf2f((unsigned short)(hv.z >> 16))    + hp1.y) * ws1.y;
          v += fast_tanh(bf2f((unsigned short)(hv.w & 0xFFFF)) + hp1.z) * ws1.z;
          v += fast_tanh(bf2f((unsigned short)(hv.w >> 16))    + hp1.w) * ws1.w;
        }
        v += __shfl_xor(v, 1, 64);
        v += __shfl_xor(v, 2, 64);
        v += __shfl_xor(v, 4, 64);
        if (li8 == 0) SE[pi] = v;   // SE[i*32+t]
      }
    }
    __syncthreads();

    // ---- C: softmax over t (32-lane groups)
    if (tid < 256) {
      float e = SE[tid];
      float mx = e;
#pragma unroll
      for (int m = 16; m >= 1; m >>= 1) mx = fmaxf(mx, __shfl_xor(mx, m, 32));
      float pexp = __expf(e - mx);
      float ssum = pexp;
#pragma unroll
      for (int m = 16; m >= 1; m >>= 1) ssum += __shfl_xor(ssum, m, 32);
      SE[tid] = pexp / ssum;
    }
    __syncthreads();

    // ---- D: context streamed from global with sc1 (L2-bypass) loads -> XA (swz)
    {
      float acc[8] = {0.f, 0.f, 0.f, 0.f, 0.f, 0.f, 0.f, 0.f};
      const float* al = SE + w * 32;
#pragma unroll 1
      for (int tb = 0; tb < 8; ++tb) {
        const u32x4* p0 = &bhsrc[(tb * 4 + 0) * 64];
        const u32x4* p1 = &bhsrc[(tb * 4 + 1) * 64];
        const u32x4* p2 = &bhsrc[(tb * 4 + 2) * 64];
        const u32x4* p3 = &bhsrc[(tb * 4 + 3) * 64];
        u32x4 h0, h1, h2, h3;
        asm volatile(
            "global_load_dwordx4 %0, %4, off sc1 nt\n\t"
            "global_load_dwordx4 %1, %5, off sc1 nt\n\t"
            "global_load_dwordx4 %2, %6, off sc1 nt\n\t"
            "global_load_dwordx4 %3, %7, off sc1 nt\n\t"
            "s_waitcnt vmcnt(0)"
            : "=&v"(h0), "=&v"(h1), "=&v"(h2), "=&v"(h3)
            : "v"(p0), "v"(p1), "v"(p2), "v"(p3));
        u32x4 hvb[4] = {h0, h1, h2, h3};
#pragma unroll
        for (int u = 0; u < 4; ++u) {
          float a = al[tb * 4 + u];
          u32x4 hv = hvb[u];
          acc[0] += a * bf2f((unsigned short)(hv.x & 0xFFFF));
          acc[1] += a * bf2f((unsigned short)(hv.x >> 16));
          acc[2] += a * bf2f((unsigned short)(hv.y & 0xFFFF));
          acc[3] += a * bf2f((unsigned short)(hv.y >> 16));
          acc[4] += a * bf2f((unsigned short)(hv.z & 0xFFFF));
          acc[5] += a * bf2f((unsigned short)(hv.z >> 16));
          acc[6] += a * bf2f((unsigned short)(hv.w & 0xFFFF));
          acc[7] += a * bf2f((unsigned short)(hv.w >> 16));
        }
      }
      uint4 o = {pk(f2bf(acc[0]), f2bf(acc[1])), pk(f2bf(acc[2]), f2bf(acc[3])),
                 pk(f2bf(acc[4]), f2bf(acc[5])), pk(f2bf(acc[6]), f2bf(acc[7]))};
      int kc = ln >> 2, q = ln & 3;
      int lane_t = q * 16 + w;
      *(uint4*)(XA + kc * 1024 + ((lane_t * 16) ^ ((kc & 7) << 4))) = o;
    }
    if (tid < 64) {
      int row = tid >> 3, sl = tid & 7;
      int kc = 16 + (sl >> 2), q = sl & 3;
      int cc0 = (sl >> 2) * 32 + q * 8;     // onehot class base for this slot
      int ch = text[(b0 + row) * NSTEP + s];
      unsigned short e8[8];
#pragma unroll
      for (int j = 0; j < 8; ++j)
        e8[j] = (cc0 + j == ch) ? (unsigned short)0x3F80 : (unsigned short)0;
      uint4 o = {pk(e8[0], e8[1]), pk(e8[2], e8[3]), pk(e8[4], e8[5]), pk(e8[6], e8[7])};
      int lane_t = q * 16 + row;
      *(uint4*)(XA + kc * 1024 + ((lane_t * 16) ^ ((kc & 7) << 4))) = o;
    }
    __syncthreads();

    // ---- E: gates MFMA; per-wave double-buffered staging, counted vmcnt, 0 barriers
    f32x4 acc[8];
#pragma unroll
    for (int n = 0; n < 8; ++n) acc[n] = (f32x4){0.f, 0.f, 0.f, 0.f};
    {
      // kc0 in buf0, kc1 in buf1 already landed (issued last E / init; drained by D)
#pragma unroll 1
      for (int kc = 0; kc < 24; kc += 2) {
        bf16x8 b0r[8];
        RDB(0, b0r);
        STAGE(kc + 2, 0);                 // overwrite buf0 with kc+2
        bf16x8 a0 = LDA(kc);
#pragma unroll
        for (int n = 0; n < 8; ++n)
          acc[n] = __builtin_amdgcn_mfma_f32_16x16x32_bf16(a0, b0r[n], acc[n], 0, 0, 0);
        asm volatile("s_waitcnt vmcnt(8)" ::: "memory");   // kc+1 landed
        __builtin_amdgcn_sched_barrier(0);
        bf16x8 b1r[8];
        RDB(1, b1r);
        STAGE(kc + 3, 1);                 // overwrite buf1 with kc+3
        bf16x8 a1 = LDA(kc + 1);
#pragma unroll
        for (int n = 0; n < 8; ++n)
          acc[n] = __builtin_amdgcn_mfma_f32_16x16x32_bf16(a1, b1r[n], acc[n], 0, 0, 0);
        asm volatile("s_waitcnt vmcnt(8)" ::: "memory");   // kc+2 landed
        __builtin_amdgcn_sched_barrier(0);
      }
      // epilogue: kc=24 ready in buf0; kc=25 staging into buf1 (8 outstanding)
      bf16x8 b0r[8];
      RDB(0, b0r);
      bf16x8 a0 = LDA(24);
#pragma unroll
      for (int n = 0; n < 8; ++n)
        acc[n] = __builtin_amdgcn_mfma_f32_16x16x32_bf16(a0, b0r[n], acc[n], 0, 0, 0);
      asm volatile("s_waitcnt vmcnt(0)" ::: "memory");     // kc=25 landed
      __builtin_amdgcn_sched_barrier(0);
      bf16x8 b1r[8];
      RDB(1, b1r);
      STAGE(0, 0);                        // prefetch next step's kc0/kc1
      STAGE(1, 1);                        // (drained for free by next D)
      bf16x8 a1 = LDA(25);
#pragma unroll
      for (int n = 0; n < 8; ++n)
        acc[n] = __builtin_amdgcn_mfma_f32_16x16x32_bf16(a1, b1r[n], acc[n], 0, 0, 0);
    }
    unsigned short hreg[2][4];
    if (qd < 2) {
#pragma unroll
      for (int k = 0; k < 2; ++k) {
        int jg = (2 * w + k) * 16 + li;
        float bci = bc[jg], bcf = bc[256 + jg], bcg = bc[512 + jg], bco = bc[768 + jg];
#pragma unroll
        for (int r = 0; r < 4; ++r) {
          float iv = fast_sigmoid(acc[k * 4 + 0][r] + bci);
          float fv = fast_sigmoid(acc[k * 4 + 1][r] + bcf);
          float gv = fast_tanh   (acc[k * 4 + 2][r] + bcg);
          float ov = fast_sigmoid(acc[k * 4 + 3][r] + bco);
          float cn = fv * cst[k][r] + iv * gv;
          cst[k][r] = cn;
          hreg[k][r] = f2bf(ov * fast_tanh(cn));
        }
      }
    }
    __syncthreads();   // all MFMA reads of h(s-1) complete before overwrite

    // ---- F: write h(s) to HL (swizzled)
    if (qd < 2) {
#pragma unroll
      for (int k = 0; k < 2; ++k) {
        int jg = (2 * w + k) * 16 + li;
#pragma unroll
        for (int r = 0; r < 4; ++r) {
          int row = qd * 4 + r;
          *(unsigned short*)(HL + row * 512 + ((jg * 2) ^ (row << 4))) = hreg[k][r];
        }
      }
    }
    __syncthreads();

    // ---- G: probs(s) = h(s) @ W_gen^T + b_gen (waves 0..2; no barrier needed after)
    if (w < 3) {
      f32x4 pa = {0.f, 0.f, 0.f, 0.f};
      const bf16x8* W8 = (const bf16x8*)Wgp;
#pragma unroll
      for (int kc = 0; kc < 8; ++kc) {
        bf16x8 a = *(const bf16x8*)(HL + hrow * 512 + ((kc * 64 + qd * 16) ^ (hrow << 4)));
        bf16x8 b = W8[(w * 8 + kc) * 64 + ln];
        pa = __builtin_amdgcn_mfma_f32_16x16x32_bf16(a, b, pa, 0, 0, 0);
      }
      int col = w * 16 + li;
      if (qd < 2 && col < NCLS) {
        float bg = b_gen[col];
#pragma unroll
        for (int r = 0; r < 4; ++r) {
          int row = qd * 4 + r;
          out[((size_t)(b0 + row) * NSTEP + s) * NCLS + col] = pa[r] + bg;
        }
      }
    }
  }
}

// ---------------------------------------------------------------------------
extern "C" void kernel_launch(void* const* d_in, const int* in_sizes, int n_in,
                              void* d_out, int out_size, void* d_ws, size_t ws_size,
                              hipStream_t stream) {
  const float* batch_H = (const float*)d_in[0];
  const int*   text    = (const int*)d_in[1];
  const float* W_i2h   = (const float*)d_in[2];
  const float* W_h2h   = (const float*)d_in[3];
  const float* b_h2h   = (const float*)d_in[4];
  const float* W_score = (const float*)d_in[5];
  const float* W_ih    = (const float*)d_in[6];
  const float* b_ih    = (const float*)d_in[7];
  const float* W_hh    = (const float*)d_in[8];
  const float* b_hh    = (const float*)d_in[9];
  const float* W_gen   = (const float*)d_in[10];
  const float* b_gen   = (const float*)d_in[11];
  float* out = (float*)d_out;

  // workspace layout (bytes)
  char* p = (char*)d_ws;
  unsigned short* bHbf = (unsigned short*)p;  p += (size_t)2048 * 32 * 512 * 2;  // 64 MiB
  unsigned short* Hbf  = (unsigned short*)p;  p += (size_t)65536 * 256 * 2;      // 32 MiB
  unsigned short* Wg   = (unsigned short*)p;  p += (size_t)64 * NKC * 64 * 8 * 2;
  unsigned short* Wi   = (unsigned short*)p;  p += (size_t)256 * 512 * 2;
  unsigned short* Wgp  = (unsigned short*)p;  p += (size_t)3 * 8 * 64 * 8 * 2;
  unsigned short* Whb  = (unsigned short*)p;  p += (size_t)16 * 8 * 64 * 8 * 2;
  float* bc            = (float*)p;           p += (size_t)1024 * 4;

  static int attr_done = 0;
  if (!attr_done) {
    hipFuncSetAttribute((const void*)decode_kernel,
                        hipFuncAttributeMaxDynamicSharedMemorySize, LDS_TOTAL);
    attr_done = 1;
  }

  cvt_bh_kernel<<<16384, 256, 0, stream>>>(batch_H, bHbf);
  prep_wg_kernel<<<416, 256, 0, stream>>>(W_ih, W_hh, Wg);
  prep_wi_kernel<<<64, 256, 0, stream>>>(W_i2h, Wi);
  prep_wgen_kernel<<<6, 256, 0, stream>>>(W_gen, Wgp);
  prep_whb_bc_kernel<<<32, 256, 0, stream>>>(W_h2h, b_ih, b_hh, Whb, bc);
  hproj_mfma_kernel<<<512, 256, 0, stream>>>(bHbf, Wi, Hbf);
  decode_kernel<<<256, 512, LDS_TOTAL, stream>>>(bHbf, Hbf, Wg, Whb, Wgp, bc,
                                                 b_h2h, W_score, b_gen, text, out);
}